// Round 7
// baseline (19771.628 us; speedup 1.0000x reference)
//
#include <hip/hip_runtime.h>
#include <math.h>

#define DIM 768
#define LAYERS 12
#define NH 12
#define HDIM 64
#define FFDIM 3072
#define SEQ 256
#define BATCH 8
#define MTOK (BATCH*SEQ)   // 2048
#define TASKS 3
#define LRANK 16
#define LORA_SC 2.0f
#define QKVLD 2304
#define ZB (BATCH*NH)      // 96
#define GRID 512

typedef unsigned short u16;
typedef __attribute__((ext_vector_type(8))) short short8;
typedef __attribute__((ext_vector_type(4))) float floatx4;
typedef __attribute__((ext_vector_type(4))) unsigned short u16x4;

__device__ __forceinline__ u16 f2bf(float f) {
    unsigned int u = __float_as_uint(f);
    u = (u + 0x7fff + ((u >> 16) & 1)) >> 16;
    return (u16)u;
}

__device__ __forceinline__ float geluf(float x) {
    float u = 0.7978845608028654f * (x + 0.044715f * x * x * x);
    u = fminf(fmaxf(u, -15.f), 15.f);
    float e = __expf(2.f * u);
    float th = (e - 1.f) / (e + 1.f);
    return 0.5f * x * (1.f + th);
}

__device__ __forceinline__ float block_sum256(float v, volatile float* sb4) {
    #pragma unroll
    for (int o = 32; o; o >>= 1) v += __shfl_down(v, o);
    int w = threadIdx.x >> 6;
    if ((threadIdx.x & 63) == 0) sb4[w] = v;
    __syncthreads();
    float total = sb4[0] + sb4[1] + sb4[2] + sb4[3];
    __syncthreads();
    return total;
}

// ---- software grid barrier (the pattern grid.sync() lowers to) ----
// bar[0] = monotonic arrival counter (cacheline 0), bar[32] = release gen (cacheline 1).
// All blocks co-resident by construction: 512 blocks x 64KB LDS = 2/CU (128 of 160KB),
// __launch_bounds__(256,2) caps VGPR at 256 so occupancy cannot drop below 2/CU.
__device__ __forceinline__ void gsync(unsigned* bar, unsigned& gen) {
    gen++;
    __syncthreads();
    __threadfence();
    if (threadIdx.x == 0) {
        unsigned arr = atomicAdd(&bar[0], 1u) + 1;
        if (arr == gen * GRID) {
            atomicExch(&bar[32], gen);
        } else {
            unsigned tries = 0;
            while (atomicAdd(&bar[32], 0u) < gen) {
                __builtin_amdgcn_s_sleep(2);
                if (++tries > 200000000u) break;   // failsafe: fail loud, don't hang
            }
        }
    }
    __threadfence();
    __syncthreads();
}

// ============ prep kernels (regular launches) ============
__global__ __launch_bounds__(256) void w_transpose64(
    const float* __restrict__ src, size_t src_ls,
    u16* __restrict__ dst, size_t dst_ls, int N, int dstld, int row_off) {
    __shared__ float tile[64][65];
    int l = blockIdx.z;
    int k0 = blockIdx.y * 64, n0 = blockIdx.x * 64;
    int t = threadIdx.x;
    int r = t >> 4, c4 = (t & 15) * 4;
    const float* s = src + (size_t)l * src_ls + (size_t)k0 * N + n0;
    #pragma unroll
    for (int i = 0; i < 4; ++i) {
        float4 v = *(const float4*)&s[(size_t)(r + i * 16) * N + c4];
        tile[r + i * 16][c4 + 0] = v.x; tile[r + i * 16][c4 + 1] = v.y;
        tile[r + i * 16][c4 + 2] = v.z; tile[r + i * 16][c4 + 3] = v.w;
    }
    __syncthreads();
    u16* d = dst + (size_t)l * dst_ls;
    #pragma unroll
    for (int i = 0; i < 4; ++i) {
        int n = r + i * 16;
        u16x4 o;
        o[0] = f2bf(tile[c4 + 0][n]); o[1] = f2bf(tile[c4 + 1][n]);
        o[2] = f2bf(tile[c4 + 2][n]); o[3] = f2bf(tile[c4 + 3][n]);
        *(u16x4*)&d[(size_t)(row_off + n0 + n) * dstld + k0 + c4] = o;
    }
}

__global__ __launch_bounds__(256) void build_bqkv(
    const float* __restrict__ bq, const float* __restrict__ bk,
    const float* __restrict__ bv, float* __restrict__ bqkv) {
    int l = blockIdx.x;
    for (int i = threadIdx.x; i < QKVLD; i += 256) {
        float v = i < DIM ? bq[l * DIM + i]
                : (i < 2 * DIM ? bk[l * DIM + i - DIM] : bv[l * DIM + i - 2 * DIM]);
        bqkv[(size_t)l * QKVLD + i] = v;
    }
}

// ============ GEMM core (dbuf + counted vmcnt), device-side ============
template<int ROWS>
__device__ __forceinline__ void stage_tile(const u16* srcbase, int ldk,
                                           u16* ldsbase, int wave, int lane) {
    int rin = lane >> 3, slot = lane & 7;
    #pragma unroll
    for (int c0 = 0; c0 < ROWS / 8; c0 += 4) {
        int c = c0 + wave;
        int r = c * 8 + rin;
        int scol = ((slot ^ (r & 7)) << 3);
        const u16* src = srcbase + (size_t)r * ldk + scol;
        __builtin_amdgcn_global_load_lds(
            (const __attribute__((address_space(1))) unsigned int*)src,
            (__attribute__((address_space(3))) unsigned int*)(ldsbase + (size_t)c * 512 + lane * 8),
            16, 0, 0);
    }
}

__device__ __forceinline__ short8 frag_read(const u16* ldsbase, int r, int s) {
    return *(const short8*)(ldsbase + r * 64 + (((s ^ (r & 7)) << 3)));
}

// K/64 must be EVEN at all call sites (K=768 -> 12, K=3072 -> 48).
template<int BM, int BN>
__device__ __forceinline__ void gemm_core(
    const u16* __restrict__ A, int lda, const u16* __restrict__ B, int ldb,
    int K, int m0, int n0, u16* lds, floatx4 (&acc)[BM / 32][BN / 32]) {
    constexpr int TILE = (BM + BN) * 64;
    constexpr int NL = BM / 32 + BN / 32;
    u16* buf0 = lds;
    u16* buf1 = lds + TILE;
    int t = threadIdx.x, lane = t & 63, wave = t >> 6;
    int wr = wave >> 1, wc = wave & 1;
    constexpr int FM = BM / 32, FN = BN / 32;
    int wm0 = wr * (BM / 2), wn0 = wc * (BN / 2);
    #pragma unroll
    for (int i = 0; i < FM; ++i)
        #pragma unroll
        for (int j = 0; j < FN; ++j)
            acc[i][j] = (floatx4){0.f, 0.f, 0.f, 0.f};
    int lr = lane & 15, kg = lane >> 4;
    const u16* Abase = A + (size_t)m0 * lda;
    const u16* Bbase = B + (size_t)n0 * ldb;

    auto stage = [&](u16* dst, int k0) {
        stage_tile<BM>(Abase + k0, lda, dst, wave, lane);
        stage_tile<BN>(Bbase + k0, ldb, dst + BM * 64, wave, lane);
    };
    auto compute = [&](const u16* buf) {
        const u16* As = buf;
        const u16* Bs = buf + BM * 64;
        #pragma unroll
        for (int kk = 0; kk < 2; ++kk) {
            short8 af[FM], bfr[FN];
            #pragma unroll
            for (int mi = 0; mi < FM; ++mi)
                af[mi] = frag_read(As, wm0 + mi * 16 + lr, kk * 4 + kg);
            #pragma unroll
            for (int ni = 0; ni < FN; ++ni)
                bfr[ni] = frag_read(Bs, wn0 + ni * 16 + lr, kk * 4 + kg);
            #pragma unroll
            for (int mi = 0; mi < FM; ++mi)
                #pragma unroll
                for (int ni = 0; ni < FN; ++ni)
                    acc[mi][ni] = __builtin_amdgcn_mfma_f32_16x16x32_bf16(
                        af[mi], bfr[ni], acc[mi][ni], 0, 0, 0);
        }
    };

    int nt = K / 64;
    stage(buf0, 0);
    for (int ti = 0; ti < nt; ti += 2) {
        stage(buf1, (ti + 1) * 64);
        asm volatile("s_waitcnt vmcnt(%0)" :: "n"(NL) : "memory");
        __builtin_amdgcn_s_barrier();
        __builtin_amdgcn_sched_barrier(0);
        compute(buf0);
        __builtin_amdgcn_sched_barrier(0);
        __builtin_amdgcn_s_barrier();
        if (ti + 2 < nt) {
            stage(buf0, (ti + 2) * 64);
            asm volatile("s_waitcnt vmcnt(%0)" :: "n"(NL) : "memory");
        } else {
            asm volatile("s_waitcnt vmcnt(0)" ::: "memory");
        }
        __builtin_amdgcn_s_barrier();
        __builtin_amdgcn_sched_barrier(0);
        compute(buf1);
        __builtin_amdgcn_sched_barrier(0);
        __builtin_amdgcn_s_barrier();
    }
}

// ============ megakernel args ============
struct MegaArgs {
    const int* ids; const int* mask;
    const float* wemb; const float* pemb; const float* emb_g; const float* emb_b;
    const u16* WqkvT; const u16* WoT; const u16* WiT; const u16* Wo2T;
    const float* bqkv; const float* bo; const float* bi; const float* bo2;
    const float* g1; const float* b1; const float* g2; const float* b2;
    const float* rW1; const float* rb1; const float* rW2; const float* rb2;
    const float* temp;
    const float* qA; const float* qB; const float* vA; const float* vB;
    const float* cW1; const float* cb1; const float* cW2; const float* cb2;
    float* h; float* h2; u16* h_bf; u16* o_bf; u16* qkv_bf; u16* ffb_bf; u16* vT;
    float* tq; float* tv; float* y1; int* task; float* out;
    unsigned* bar;
};

// ============ phase device functions ============
__device__ __forceinline__ void embed_row(
    const MegaArgs& a, int m, int t, volatile float* sb4) {
    int s = m & (SEQ - 1);
    int id = a.ids[m];
    float x[3];
    float sum = 0.f;
    #pragma unroll
    for (int j = 0; j < 3; ++j) {
        int d = t + j * 256;
        x[j] = a.wemb[(size_t)id * DIM + d] + a.pemb[(size_t)(s + 2) * DIM + d];
        sum += x[j];
    }
    float mean = block_sum256(sum, sb4) * (1.0f / DIM);
    float vs = 0.f;
    #pragma unroll
    for (int j = 0; j < 3; ++j) { float c = x[j] - mean; vs += c * c; }
    float var = block_sum256(vs, sb4) * (1.0f / DIM);
    float rstd = rsqrtf(var + 1e-5f);
    #pragma unroll
    for (int j = 0; j < 3; ++j) {
        int d = t + j * 256;
        float r = (x[j] - mean) * rstd * a.emb_g[d] + a.emb_b[d];
        a.h[(size_t)m * DIM + d] = r;
        a.h_bf[(size_t)m * DIM + d] = f2bf(r);
    }
}

__device__ __forceinline__ void add_ln_row(
    float* h, const float* proj, const float* g, const float* bb,
    u16* h_bf, int m, int t, volatile float* sb4) {
    float x[3];
    float sum = 0.f;
    #pragma unroll
    for (int j = 0; j < 3; ++j) {
        int d = t + j * 256;
        x[j] = h[(size_t)m * DIM + d] + proj[(size_t)m * DIM + d];
        sum += x[j];
    }
    float mean = block_sum256(sum, sb4) * (1.0f / DIM);
    float vs = 0.f;
    #pragma unroll
    for (int j = 0; j < 3; ++j) { float c = x[j] - mean; vs += c * c; }
    float var = block_sum256(vs, sb4) * (1.0f / DIM);
    float rstd = rsqrtf(var + 1e-5f);
    #pragma unroll
    for (int j = 0; j < 3; ++j) {
        int d = t + j * 256;
        float r = (x[j] - mean) * rstd * g[d] + bb[d];
        h[(size_t)m * DIM + d] = r;
        h_bf[(size_t)m * DIM + d] = f2bf(r);
    }
}

template<int BM, int BN, int ACT, int OUTMODE>   // OUTMODE: 0=f32, 1=bf16
__device__ __forceinline__ void gemm_tile(
    const u16* A, int lda, const u16* B, int ldb, const float* bias,
    float* Cf, u16* Cb, int ldc, int K, int m0, int n0, int t, u16* lds) {
    constexpr int FM = BM / 32, FN = BN / 32;
    floatx4 acc[FM][FN];
    gemm_core<BM, BN>(A, lda, B, ldb, K, m0, n0, lds, acc);
    int lane = t & 63, wave = t >> 6;
    int wr = wave >> 1, wc = wave & 1;
    int wm0 = wr * (BM / 2), wn0 = wc * (BN / 2);
    int cr = (lane >> 4) * 4, cc = lane & 15;
    #pragma unroll
    for (int mi = 0; mi < FM; ++mi) {
        #pragma unroll
        for (int ni = 0; ni < FN; ++ni) {
            int col = n0 + wn0 + ni * 16 + cc;
            float bsv = bias ? bias[col] : 0.f;
            #pragma unroll
            for (int j = 0; j < 4; ++j) {
                int row = m0 + wm0 + mi * 16 + cr + j;
                float r = acc[mi][ni][j] + bsv;
                if (ACT == 1) r = geluf(r);
                if (OUTMODE == 0) Cf[(size_t)row * ldc + col] = r;
                else Cb[(size_t)row * ldc + col] = f2bf(r);
            }
        }
    }
}

template<int LORA>
__device__ __forceinline__ void qkv_tile(
    const MegaArgs& a, const u16* Bw, const float* bias, int layer,
    int m0, int n0, int t, u16* lds) {
    floatx4 acc[4][4];
    gemm_core<128, 128>(a.h_bf, DIM, Bw, DIM, DIM, m0, n0, lds, acc);
    int lane = t & 63, wave = t >> 6;
    int wr = wave >> 1, wc = wave & 1;
    int wm0 = wr * 64, wn0 = wc * 64;
    int cr = (lane >> 4) * 4, cc = lane & 15;
    const float* tvec = nullptr;
    const float* Bmat = nullptr;
    if (LORA) {
        int tk = a.task[m0 >> 8];
        if (n0 < DIM) {
            tvec = a.tq;
            Bmat = a.qB + ((size_t)tk * LAYERS + layer) * DIM * LRANK;
        } else if (n0 >= 2 * DIM) {
            tvec = a.tv;
            Bmat = a.vB + ((size_t)tk * LAYERS + layer) * DIM * LRANK - (size_t)2 * DIM * LRANK;
        }
    }
    bool vrange = (n0 >= 2 * DIM);
    #pragma unroll
    for (int mi = 0; mi < 4; ++mi) {
        #pragma unroll
        for (int j = 0; j < 4; ++j) {
            int row = m0 + wm0 + mi * 16 + cr + j;
            float4 t0, t1, t2, t3;
            if (LORA && tvec) {
                const float* tp = tvec + (size_t)row * LRANK;
                t0 = *(const float4*)(tp + 0);  t1 = *(const float4*)(tp + 4);
                t2 = *(const float4*)(tp + 8);  t3 = *(const float4*)(tp + 12);
            }
            #pragma unroll
            for (int ni = 0; ni < 4; ++ni) {
                int col = n0 + wn0 + ni * 16 + cc;
                float r = acc[mi][ni][j] + bias[col];
                if (LORA && tvec) {
                    const float* bp = Bmat + (size_t)col * LRANK;
                    float4 b0 = *(const float4*)(bp + 0),  b1 = *(const float4*)(bp + 4);
                    float4 b2 = *(const float4*)(bp + 8),  b3 = *(const float4*)(bp + 12);
                    float d = t0.x * b0.x + t0.y * b0.y + t0.z * b0.z + t0.w * b0.w
                            + t1.x * b1.x + t1.y * b1.y + t1.z * b1.z + t1.w * b1.w
                            + t2.x * b2.x + t2.y * b2.y + t2.z * b2.z + t2.w * b2.w
                            + t3.x * b3.x + t3.y * b3.y + t3.z * b3.z + t3.w * b3.w;
                    r += LORA_SC * d;
                }
                u16 rb = f2bf(r);
                a.qkv_bf[(size_t)row * QKVLD + col] = rb;
                if (vrange) {
                    int vcol = col - 2 * DIM;
                    int hh = vcol >> 6, dd = vcol & 63;
                    int bb = row >> 8, kpos = row & 255;
                    a.vT[((size_t)(bb * NH + hh) * HDIM + dd) * SEQ + kpos] = rb;
                }
            }
        }
    }
}

// ---- fused attention unit ----
__device__ __forceinline__ int lds256_idx(int r, int col) {
    int sub = col >> 6, inner = col & 63;
    return r * 256 + sub * 64 + ((((inner >> 3) ^ (r & 7))) << 3) + (inner & 7);
}
__device__ __forceinline__ short8 frag_read256(const u16* base, int r, int kk, int kg) {
    int col = kk * 32 + kg * 8;
    int sub = col >> 6, slot = (col & 63) >> 3;
    return *(const short8*)(base + r * 256 + sub * 64 + ((slot ^ (r & 7)) << 3));
}

__device__ __forceinline__ void attn_unit(
    const MegaArgs& a, int qt, int z, int t, u16* lds) {
    u16* KV = lds;
    u16* P = lds + 256 * 64;
    int b = z / NH, h = z % NH;
    int lane = t & 63, w = t >> 6;
    int cc = lane & 15, q4 = lane >> 4;

    float mb[16];
    #pragma unroll
    for (int ni = 0; ni < 16; ++ni)
        mb[ni] = (1.0f - (float)a.mask[b * SEQ + ni * 16 + cc]) * -1e9f;

    int qrow = b * SEQ + qt * 64 + w * 16 + cc;
    const u16* qp = a.qkv_bf + (size_t)qrow * QKVLD + h * HDIM + q4 * 8;
    short8 qa0 = *(const short8*)(qp);
    short8 qa1 = *(const short8*)(qp + 32);

    stage_tile<256>(a.qkv_bf + (size_t)(b * SEQ) * QKVLD + DIM + h * HDIM, QKVLD, KV, w, lane);
    __syncthreads();

    floatx4 s[16];
    #pragma unroll
    for (int ni = 0; ni < 16; ++ni) s[ni] = (floatx4){0.f, 0.f, 0.f, 0.f};
    #pragma unroll
    for (int kk = 0; kk < 2; ++kk) {
        short8 qa = kk == 0 ? qa0 : qa1;
        #pragma unroll
        for (int ni = 0; ni < 16; ++ni) {
            short8 kf = frag_read(KV, ni * 16 + cc, kk * 4 + q4);
            s[ni] = __builtin_amdgcn_mfma_f32_16x16x32_bf16(qa, kf, s[ni], 0, 0, 0);
        }
    }

    float pv[16][4];
    float mrow[4] = {-1e30f, -1e30f, -1e30f, -1e30f};
    #pragma unroll
    for (int ni = 0; ni < 16; ++ni)
        #pragma unroll
        for (int j = 0; j < 4; ++j) {
            float v = s[ni][j] * 0.125f + mb[ni];
            pv[ni][j] = v;
            mrow[j] = fmaxf(mrow[j], v);
        }
    #pragma unroll
    for (int o = 1; o < 16; o <<= 1)
        #pragma unroll
        for (int j = 0; j < 4; ++j) mrow[j] = fmaxf(mrow[j], __shfl_xor(mrow[j], o));
    float srow[4] = {0.f, 0.f, 0.f, 0.f};
    #pragma unroll
    for (int ni = 0; ni < 16; ++ni)
        #pragma unroll
        for (int j = 0; j < 4; ++j) {
            float e = __expf(pv[ni][j] - mrow[j]);
            pv[ni][j] = e;
            srow[j] += e;
        }
    #pragma unroll
    for (int o = 1; o < 16; o <<= 1)
        #pragma unroll
        for (int j = 0; j < 4; ++j) srow[j] += __shfl_xor(srow[j], o);
    float inv[4];
    #pragma unroll
    for (int j = 0; j < 4; ++j) inv[j] = 1.0f / srow[j];

    u16* Pw = P + w * 16 * 256;
    #pragma unroll
    for (int ni = 0; ni < 16; ++ni)
        #pragma unroll
        for (int j = 0; j < 4; ++j)
            Pw[lds256_idx(q4 * 4 + j, ni * 16 + cc)] = f2bf(pv[ni][j] * inv[j]);
    __syncthreads();

    {
        const u16* vz = a.vT + (size_t)z * HDIM * SEQ;
        int rin = lane >> 3, slot = lane & 7;
        #pragma unroll
        for (int c0 = 0; c0 < 32; c0 += 4) {
            int c = c0 + w;
            int vrow = c * 8 + rin;
            int d = vrow >> 2, sub = vrow & 3;
            const u16* src = vz + d * 256 + sub * 64 + (((slot ^ (d & 7))) << 3);
            __builtin_amdgcn_global_load_lds(
                (const __attribute__((address_space(1))) unsigned int*)src,
                (__attribute__((address_space(3))) unsigned int*)(KV + c * 512 + lane * 8),
                16, 0, 0);
        }
    }
    __syncthreads();

    floatx4 oa[4];
    #pragma unroll
    for (int ni = 0; ni < 4; ++ni) oa[ni] = (floatx4){0.f, 0.f, 0.f, 0.f};
    #pragma unroll
    for (int kk = 0; kk < 8; ++kk) {
        short8 pf = frag_read256(Pw, cc, kk, q4);
        #pragma unroll
        for (int ni = 0; ni < 4; ++ni) {
            short8 vf = frag_read256(KV, ni * 16 + cc, kk, q4);
            oa[ni] = __builtin_amdgcn_mfma_f32_16x16x32_bf16(pf, vf, oa[ni], 0, 0, 0);
        }
    }
    #pragma unroll
    for (int ni = 0; ni < 4; ++ni)
        #pragma unroll
        for (int j = 0; j < 4; ++j) {
            int m = b * SEQ + qt * 64 + w * 16 + q4 * 4 + j;
            a.o_bf[(size_t)m * DIM + h * HDIM + ni * 16 + cc] = f2bf(oa[ni][j]);
        }
}

// ---- LoRA t-vectors unit ----
__device__ __forceinline__ void lora_t_unit(
    const MegaArgs& a, int layer, int u, int t) {
    int which = u & 1;
    const float* Ab = which ? a.vA : a.qA;
    float* tout = which ? a.tv : a.tq;
    int m0 = (u >> 1) * 64;
    int tk = a.task[m0 >> 8];
    const float* Ap = Ab + ((size_t)tk * LAYERS + layer) * LRANK * DIM;
    int row = t & 63, rb = t >> 6;
    float s[4] = {0.f, 0.f, 0.f, 0.f};
    const float* hrow = a.h + (size_t)(m0 + row) * DIM;
    for (int d = 0; d < DIM; d += 4) {
        float4 hv = *(const float4*)&hrow[d];
        #pragma unroll
        for (int i = 0; i < 4; ++i) {
            float4 av = *(const float4*)&Ap[(size_t)(rb + i * 4) * DIM + d];
            s[i] += hv.x * av.x + hv.y * av.y + hv.z * av.z + hv.w * av.w;
        }
    }
    #pragma unroll
    for (int i = 0; i < 4; ++i)
        tout[(size_t)(m0 + row) * LRANK + rb + i * 4] = s[i];
}

// ---- heads ----
template<int TANH>
__device__ __forceinline__ void head1_unit(
    const float* h, const float* W1base, const float* b1base,
    const int* taskp, float* y1, int u, int t, u16* lds) {
    int b = u / 12;
    int c0 = (u % 12) * 64;
    int tk = taskp ? taskp[b] : 0;
    const float* W1 = W1base + (size_t)tk * DIM * DIM;
    const float* b1 = b1base + (size_t)tk * DIM;
    float* cls = (float*)lds;
    float* part = cls + DIM;
    for (int j = t; j < DIM; j += 256) cls[j] = h[(size_t)(b * SEQ) * DIM + j];
    __syncthreads();
    int col = c0 + (t & 63);
    int seg = t >> 6;
    float s = 0.f;
    #pragma unroll 4
    for (int d = seg * 192; d < seg * 192 + 192; ++d)
        s += cls[d] * W1[(size_t)d * DIM + col];
    part[seg * 64 + (t & 63)] = s;
    __syncthreads();
    if (t < 64) {
        float r = part[t] + part[64 + t] + part[128 + t] + part[192 + t] + b1[c0 + t];
        y1[(size_t)b * DIM + c0 + t] = TANH ? tanhf(r) : fmaxf(r, 0.f);
    }
}

__device__ __forceinline__ void router_fin_unit(
    const MegaArgs& a, int b, int t, u16* lds) {
    float* red = (float*)lds;
    float p[3] = {0.f, 0.f, 0.f};
    #pragma unroll
    for (int j = 0; j < 3; ++j) {
        int col = t + j * 256;
        float y = a.y1[(size_t)b * DIM + col];
        p[0] += y * a.rW2[col * 3 + 0];
        p[1] += y * a.rW2[col * 3 + 1];
        p[2] += y * a.rW2[col * 3 + 2];
    }
    #pragma unroll
    for (int o = 32; o; o >>= 1) {
        p[0] += __shfl_down(p[0], o);
        p[1] += __shfl_down(p[1], o);
        p[2] += __shfl_down(p[2], o);
    }
    int w = t >> 6;
    if ((t & 63) == 0) { red[0 * 4 + w] = p[0]; red[1 * 4 + w] = p[1]; red[2 * 4 + w] = p[2]; }
    __syncthreads();
    if (t == 0) {
        float tt = fmaxf(a.temp[0], 0.05f);
        float l[3];
        #pragma unroll
        for (int c = 0; c < 3; ++c) {
            l[c] = (red[c * 4 + 0] + red[c * 4 + 1] + red[c * 4 + 2] + red[c * 4 + 3] + a.rb2[c]) / tt;
            a.out[b * 3 + c] = l[c];
        }
        int bt = 0; float bv = l[0];
        if (l[1] > bv) { bv = l[1]; bt = 1; }
        if (l[2] > bv) { bv = l[2]; bt = 2; }
        a.task[b] = bt;
    }
}

__device__ __forceinline__ void cls_fin_unit(
    const MegaArgs& a, int b, int t, u16* lds) {
    float* red = (float*)lds;
    int tk = a.task[b];
    const float* W2 = a.cW2 + (size_t)tk * DIM * 2;
    const float* b2 = a.cb2 + tk * 2;
    float p[2] = {0.f, 0.f};
    #pragma unroll
    for (int j = 0; j < 3; ++j) {
        int col = t + j * 256;
        float y = a.y1[(size_t)b * DIM + col];
        p[0] += y * W2[col * 2 + 0];
        p[1] += y * W2[col * 2 + 1];
    }
    #pragma unroll
    for (int o = 32; o; o >>= 1) {
        p[0] += __shfl_down(p[0], o);
        p[1] += __shfl_down(p[1], o);
    }
    int w = t >> 6;
    if ((t & 63) == 0) { red[0 * 4 + w] = p[0]; red[1 * 4 + w] = p[1]; }
    __syncthreads();
    if (t == 0) {
        #pragma unroll
        for (int c = 0; c < 2; ++c)
            a.out[BATCH * TASKS + b * 2 + c] =
                red[c * 4 + 0] + red[c * 4 + 1] + red[c * 4 + 2] + red[c * 4 + 3] + b2[c];
    }
}

// ============ the megakernel (plain launch + software grid barrier) ============
template<int PASS>
__global__ __launch_bounds__(256, 2) void encoder_mega(MegaArgs a) {
    __shared__ __align__(16) u16 lds[32768];   // 64 KB union -> exactly 2 blocks/CU
    const int bid = blockIdx.x;
    const int t = threadIdx.x;
    volatile float* sb4 = (volatile float*)lds;
    unsigned gen = 0;
    unsigned* bar = a.bar;

    for (int m = bid; m < MTOK; m += GRID)
        embed_row(a, m, t, sb4);
    gsync(bar, gen);

    for (int l = 0; l < LAYERS; ++l) {
        const u16* WqkvT_l = a.WqkvT + (size_t)l * QKVLD * DIM;
        const u16* WoT_l   = a.WoT   + (size_t)l * DIM * DIM;
        const u16* WiT_l   = a.WiT   + (size_t)l * FFDIM * DIM;
        const u16* Wo2T_l  = a.Wo2T  + (size_t)l * DIM * FFDIM;
        const float* bqkv_l = a.bqkv + (size_t)l * QKVLD;
        const float* bo_l  = a.bo  + (size_t)l * DIM;
        const float* bi_l  = a.bi  + (size_t)l * FFDIM;
        const float* bo2_l = a.bo2 + (size_t)l * DIM;
        const float* g1_l  = a.g1  + (size_t)l * DIM;
        const float* b1_l  = a.b1  + (size_t)l * DIM;
        const float* g2_l  = a.g2  + (size_t)l * DIM;
        const float* b2_l  = a.b2  + (size_t)l * DIM;

        if (PASS == 1) {
            for (int u = bid; u < 64; u += GRID)
                lora_t_unit(a, l, u, t);
            gsync(bar, gen);
        }
        for (int u = bid; u < 288; u += GRID)
            qkv_tile<PASS>(a, WqkvT_l, bqkv_l, l, (u / 18) * 128, (u % 18) * 128, t, lds);
        gsync(bar, gen);
        for (int u = bid; u < 384; u += GRID) {
            __syncthreads();
            attn_unit(a, u & 3, u >> 2, t, lds);
        }
        gsync(bar, gen);
        for (int u = bid; u < 192; u += GRID)
            gemm_tile<64, 128, 0, 0>(a.o_bf, DIM, WoT_l, DIM, bo_l, a.h2, nullptr, DIM, DIM,
                                     (u / 6) * 64, (u % 6) * 128, t, lds);
        gsync(bar, gen);
        for (int m = bid; m < MTOK; m += GRID)
            add_ln_row(a.h, a.h2, g1_l, b1_l, a.h_bf, m, t, sb4);
        gsync(bar, gen);
        for (int u = bid; u < 384; u += GRID)
            gemm_tile<128, 128, 1, 1>(a.h_bf, DIM, WiT_l, DIM, bi_l, nullptr, a.ffb_bf, FFDIM, DIM,
                                      (u / 24) * 128, (u % 24) * 128, t, lds);
        gsync(bar, gen);
        for (int u = bid; u < 192; u += GRID)
            gemm_tile<64, 128, 0, 0>(a.ffb_bf, FFDIM, Wo2T_l, FFDIM, bo2_l, a.h2, nullptr, DIM, FFDIM,
                                     (u / 6) * 64, (u % 6) * 128, t, lds);
        gsync(bar, gen);
        for (int m = bid; m < MTOK; m += GRID)
            add_ln_row(a.h, a.h2, g2_l, b2_l, a.h_bf, m, t, sb4);
        gsync(bar, gen);
    }

    if (PASS == 0) {
        for (int u = bid; u < 96; u += GRID) {
            __syncthreads();
            head1_unit<0>(a.h, a.rW1, a.rb1, nullptr, a.y1, u, t, lds);
        }
        gsync(bar, gen);
        if (bid < BATCH)
            router_fin_unit(a, bid, t, lds);
    } else {
        for (int u = bid; u < 96; u += GRID) {
            __syncthreads();
            head1_unit<1>(a.h, a.cW1, a.cb1, a.task, a.y1, u, t, lds);
        }
        gsync(bar, gen);
        if (bid < BATCH)
            cls_fin_unit(a, bid, t, lds);
    }
}

extern "C" void kernel_launch(void* const* d_in, const int* in_sizes, int n_in,
                              void* d_out, int out_size, void* d_ws, size_t ws_size,
                              hipStream_t stream) {
    (void)in_sizes; (void)n_in; (void)out_size; (void)ws_size;
    const int*   ids   = (const int*)d_in[0];
    const int*   mask  = (const int*)d_in[1];
    const float* wemb  = (const float*)d_in[2];
    const float* pemb  = (const float*)d_in[3];
    const float* emb_g = (const float*)d_in[4];
    const float* emb_b = (const float*)d_in[5];
    const float* Wq    = (const float*)d_in[6];
    const float* Wk    = (const float*)d_in[7];
    const float* Wv    = (const float*)d_in[8];
    const float* Wo    = (const float*)d_in[9];
    const float* Wi    = (const float*)d_in[10];
    const float* Wo2   = (const float*)d_in[11];
    const float* bq    = (const float*)d_in[12];
    const float* bk    = (const float*)d_in[13];
    const float* bv    = (const float*)d_in[14];
    const float* bo    = (const float*)d_in[15];
    const float* bi    = (const float*)d_in[16];
    const float* bo2   = (const float*)d_in[17];
    const float* g1    = (const float*)d_in[18];
    const float* b1    = (const float*)d_in[19];
    const float* g2    = (const float*)d_in[20];
    const float* b2    = (const float*)d_in[21];
    const float* rW1   = (const float*)d_in[22];
    const float* rb1   = (const float*)d_in[23];
    const float* rW2   = (const float*)d_in[24];
    const float* rb2   = (const float*)d_in[25];
    const float* temp  = (const float*)d_in[26];
    const float* qA    = (const float*)d_in[27];
    const float* qB    = (const float*)d_in[28];
    const float* vA    = (const float*)d_in[29];
    const float* vB    = (const float*)d_in[30];
    const float* cW1   = (const float*)d_in[31];
    const float* cb1   = (const float*)d_in[32];
    const float* cW2   = (const float*)d_in[33];
    const float* cb2   = (const float*)d_in[34];
    float* out = (float*)d_out;

    const size_t MD = (size_t)MTOK * DIM;
    char* p = (char*)d_ws;
    auto alloc = [&](size_t bytes) { char* r = p; p += (bytes + 255) & ~(size_t)255; return r; };
    float* h      = (float*)alloc(MD * 4);
    float* h2     = (float*)alloc(MD * 4);
    u16* h_bf   = (u16*)alloc(MD * 2);
    u16* o_bf   = (u16*)alloc(MD * 2);
    u16* qkv_bf = (u16*)alloc((size_t)MTOK * QKVLD * 2);
    u16* ffb_bf = (u16*)alloc((size_t)MTOK * FFDIM * 2);
    u16* vT     = (u16*)alloc((size_t)ZB * HDIM * SEQ * 2);
    float* tq   = (float*)alloc((size_t)MTOK * LRANK * 4);
    float* tv   = (float*)alloc((size_t)MTOK * LRANK * 4);
    float* bqkv = (float*)alloc((size_t)LAYERS * QKVLD * 4);
    float* y1   = (float*)alloc((size_t)BATCH * DIM * 4);
    int* task   = (int*)alloc(256);
    unsigned* barmem = (unsigned*)alloc(512);
    u16* WqkvT  = (u16*)alloc((size_t)LAYERS * QKVLD * DIM * 2);
    u16* WoT    = (u16*)alloc((size_t)LAYERS * DIM * DIM * 2);
    u16* WiT    = (u16*)alloc((size_t)LAYERS * FFDIM * DIM * 2);
    u16* Wo2T   = (u16*)alloc((size_t)LAYERS * DIM * FFDIM * 2);

    hipMemsetAsync(barmem, 0, 512, stream);

    dim3 blk(256);
    w_transpose64<<<dim3(12, 12, LAYERS), blk, 0, stream>>>(Wq, (size_t)DIM * DIM, WqkvT, (size_t)QKVLD * DIM, DIM, DIM, 0);
    w_transpose64<<<dim3(12, 12, LAYERS), blk, 0, stream>>>(Wk, (size_t)DIM * DIM, WqkvT, (size_t)QKVLD * DIM, DIM, DIM, DIM);
    w_transpose64<<<dim3(12, 12, LAYERS), blk, 0, stream>>>(Wv, (size_t)DIM * DIM, WqkvT, (size_t)QKVLD * DIM, DIM, DIM, 2 * DIM);
    w_transpose64<<<dim3(12, 12, LAYERS), blk, 0, stream>>>(Wo, (size_t)DIM * DIM, WoT, (size_t)DIM * DIM, DIM, DIM, 0);
    w_transpose64<<<dim3(48, 12, LAYERS), blk, 0, stream>>>(Wi, (size_t)DIM * FFDIM, WiT, (size_t)FFDIM * DIM, FFDIM, DIM, 0);
    w_transpose64<<<dim3(12, 48, LAYERS), blk, 0, stream>>>(Wo2, (size_t)FFDIM * DIM, Wo2T, (size_t)DIM * FFDIM, DIM, FFDIM, 0);
    build_bqkv<<<LAYERS, blk, 0, stream>>>(bq, bk, bv, bqkv);

    MegaArgs a;
    a.ids = ids; a.mask = mask; a.wemb = wemb; a.pemb = pemb;
    a.emb_g = emb_g; a.emb_b = emb_b;
    a.WqkvT = WqkvT; a.WoT = WoT; a.WiT = WiT; a.Wo2T = Wo2T;
    a.bqkv = bqkv; a.bo = bo; a.bi = bi; a.bo2 = bo2;
    a.g1 = g1; a.b1 = b1; a.g2 = g2; a.b2 = b2;
    a.rW1 = rW1; a.rb1 = rb1; a.rW2 = rW2; a.rb2 = rb2; a.temp = temp;
    a.qA = qA; a.qB = qB; a.vA = vA; a.vB = vB;
    a.cW1 = cW1; a.cb1 = cb1; a.cW2 = cW2; a.cb2 = cb2;
    a.h = h; a.h2 = h2; a.h_bf = h_bf; a.o_bf = o_bf;
    a.qkv_bf = qkv_bf; a.ffb_bf = ffb_bf; a.vT = vT;
    a.tq = tq; a.tv = tv; a.y1 = y1; a.task = task; a.out = out;

    a.bar = barmem;
    encoder_mega<0><<<dim3(GRID), blk, 0, stream>>>(a);
    a.bar = barmem + 64;
    encoder_mega<1><<<dim3(GRID), blk, 0, stream>>>(a);
}

// Round 8
// 8819.575 us; speedup vs baseline: 2.2418x; 2.2418x over previous
//
#include <hip/hip_runtime.h>
#include <math.h>

#define DIM 768
#define LAYERS 12
#define NH 12
#define HDIM 64
#define FFDIM 3072
#define SEQ 256
#define BATCH 8
#define MTOK (BATCH*SEQ)   // 2048
#define TASKS 3
#define LRANK 16
#define LORA_SC 2.0f
#define QKVLD 2304
#define ZB (BATCH*NH)      // 96
#define GRID 512
#define XGRP 8
#define GPB (GRID/XGRP)    // 64 blocks per arrival group

typedef unsigned short u16;
typedef __attribute__((ext_vector_type(8))) short short8;
typedef __attribute__((ext_vector_type(4))) float floatx4;
typedef __attribute__((ext_vector_type(4))) unsigned short u16x4;

__device__ __forceinline__ u16 f2bf(float f) {
    unsigned int u = __float_as_uint(f);
    u = (u + 0x7fff + ((u >> 16) & 1)) >> 16;
    return (u16)u;
}

__device__ __forceinline__ float geluf(float x) {
    float u = 0.7978845608028654f * (x + 0.044715f * x * x * x);
    u = fminf(fmaxf(u, -15.f), 15.f);
    float e = __expf(2.f * u);
    float th = (e - 1.f) / (e + 1.f);
    return 0.5f * x * (1.f + th);
}

__device__ __forceinline__ float block_sum256(float v, volatile float* sb4) {
    #pragma unroll
    for (int o = 32; o; o >>= 1) v += __shfl_down(v, o);
    int w = threadIdx.x >> 6;
    if ((threadIdx.x & 63) == 0) sb4[w] = v;
    __syncthreads();
    float total = sb4[0] + sb4[1] + sb4[2] + sb4[3];
    __syncthreads();
    return total;
}

// ---- software grid barrier, tree + load-polling ----
// bar[g*32] : per-group arrival counters (g = bid&7, XCD-local line, 64 RMWs each)
// bar[256]  : level-2 counter (8 RMWs per barrier)
// bar[288]  : release generation (atomic store; pollers use RELAXED AGENT LOADS, not RMW)
__device__ __forceinline__ void gsync(unsigned* bar, unsigned gen, int bid) {
    __syncthreads();
    if (threadIdx.x == 0) {
        __threadfence();   // release: make this block's writes agent-visible
        int g = bid & (XGRP - 1);
        unsigned arr = __hip_atomic_fetch_add(&bar[g * 32], 1u,
                        __ATOMIC_RELAXED, __HIP_MEMORY_SCOPE_AGENT) + 1;
        if (arr == gen * GPB) {
            unsigned a2 = __hip_atomic_fetch_add(&bar[256], 1u,
                           __ATOMIC_RELAXED, __HIP_MEMORY_SCOPE_AGENT) + 1;
            if (a2 == gen * XGRP)
                __hip_atomic_store(&bar[288], gen,
                                   __ATOMIC_RELAXED, __HIP_MEMORY_SCOPE_AGENT);
        }
        unsigned tries = 0;
        while (__hip_atomic_load(&bar[288],
                 __ATOMIC_RELAXED, __HIP_MEMORY_SCOPE_AGENT) < gen) {
            __builtin_amdgcn_s_sleep(4);
            if (++tries > 100000000u) break;   // failsafe: fail loud, don't hang
        }
        __threadfence();   // acquire: invalidate stale local caches
    }
    __syncthreads();
}

// ============ prep kernels (regular launches) ============
__global__ __launch_bounds__(256) void w_transpose64(
    const float* __restrict__ src, size_t src_ls,
    u16* __restrict__ dst, size_t dst_ls, int N, int dstld, int row_off) {
    __shared__ float tile[64][65];
    int l = blockIdx.z;
    int k0 = blockIdx.y * 64, n0 = blockIdx.x * 64;
    int t = threadIdx.x;
    int r = t >> 4, c4 = (t & 15) * 4;
    const float* s = src + (size_t)l * src_ls + (size_t)k0 * N + n0;
    #pragma unroll
    for (int i = 0; i < 4; ++i) {
        float4 v = *(const float4*)&s[(size_t)(r + i * 16) * N + c4];
        tile[r + i * 16][c4 + 0] = v.x; tile[r + i * 16][c4 + 1] = v.y;
        tile[r + i * 16][c4 + 2] = v.z; tile[r + i * 16][c4 + 3] = v.w;
    }
    __syncthreads();
    u16* d = dst + (size_t)l * dst_ls;
    #pragma unroll
    for (int i = 0; i < 4; ++i) {
        int n = r + i * 16;
        u16x4 o;
        o[0] = f2bf(tile[c4 + 0][n]); o[1] = f2bf(tile[c4 + 1][n]);
        o[2] = f2bf(tile[c4 + 2][n]); o[3] = f2bf(tile[c4 + 3][n]);
        *(u16x4*)&d[(size_t)(row_off + n0 + n) * dstld + k0 + c4] = o;
    }
}

__global__ __launch_bounds__(256) void build_bqkv(
    const float* __restrict__ bq, const float* __restrict__ bk,
    const float* __restrict__ bv, float* __restrict__ bqkv) {
    int l = blockIdx.x;
    for (int i = threadIdx.x; i < QKVLD; i += 256) {
        float v = i < DIM ? bq[l * DIM + i]
                : (i < 2 * DIM ? bk[l * DIM + i - DIM] : bv[l * DIM + i - 2 * DIM]);
        bqkv[(size_t)l * QKVLD + i] = v;
    }
}

// ============ GEMM core (dbuf + counted vmcnt), device-side ============
template<int ROWS>
__device__ __forceinline__ void stage_tile(const u16* srcbase, int ldk,
                                           u16* ldsbase, int wave, int lane) {
    int rin = lane >> 3, slot = lane & 7;
    #pragma unroll
    for (int c0 = 0; c0 < ROWS / 8; c0 += 4) {
        int c = c0 + wave;
        int r = c * 8 + rin;
        int scol = ((slot ^ (r & 7)) << 3);
        const u16* src = srcbase + (size_t)r * ldk + scol;
        __builtin_amdgcn_global_load_lds(
            (const __attribute__((address_space(1))) unsigned int*)src,
            (__attribute__((address_space(3))) unsigned int*)(ldsbase + (size_t)c * 512 + lane * 8),
            16, 0, 0);
    }
}

__device__ __forceinline__ short8 frag_read(const u16* ldsbase, int r, int s) {
    return *(const short8*)(ldsbase + r * 64 + (((s ^ (r & 7)) << 3)));
}

// K/64 must be EVEN at all call sites (K=768 -> 12, K=3072 -> 48).
template<int BM, int BN>
__device__ __forceinline__ void gemm_core(
    const u16* __restrict__ A, int lda, const u16* __restrict__ B, int ldb,
    int K, int m0, int n0, u16* lds, floatx4 (&acc)[BM / 32][BN / 32]) {
    constexpr int TILE = (BM + BN) * 64;
    constexpr int NL = BM / 32 + BN / 32;
    u16* buf0 = lds;
    u16* buf1 = lds + TILE;
    int t = threadIdx.x, lane = t & 63, wave = t >> 6;
    int wr = wave >> 1, wc = wave & 1;
    constexpr int FM = BM / 32, FN = BN / 32;
    int wm0 = wr * (BM / 2), wn0 = wc * (BN / 2);
    #pragma unroll
    for (int i = 0; i < FM; ++i)
        #pragma unroll
        for (int j = 0; j < FN; ++j)
            acc[i][j] = (floatx4){0.f, 0.f, 0.f, 0.f};
    int lr = lane & 15, kg = lane >> 4;
    const u16* Abase = A + (size_t)m0 * lda;
    const u16* Bbase = B + (size_t)n0 * ldb;

    auto stage = [&](u16* dst, int k0) {
        stage_tile<BM>(Abase + k0, lda, dst, wave, lane);
        stage_tile<BN>(Bbase + k0, ldb, dst + BM * 64, wave, lane);
    };
    auto compute = [&](const u16* buf) {
        const u16* As = buf;
        const u16* Bs = buf + BM * 64;
        #pragma unroll
        for (int kk = 0; kk < 2; ++kk) {
            short8 af[FM], bfr[FN];
            #pragma unroll
            for (int mi = 0; mi < FM; ++mi)
                af[mi] = frag_read(As, wm0 + mi * 16 + lr, kk * 4 + kg);
            #pragma unroll
            for (int ni = 0; ni < FN; ++ni)
                bfr[ni] = frag_read(Bs, wn0 + ni * 16 + lr, kk * 4 + kg);
            #pragma unroll
            for (int mi = 0; mi < FM; ++mi)
                #pragma unroll
                for (int ni = 0; ni < FN; ++ni)
                    acc[mi][ni] = __builtin_amdgcn_mfma_f32_16x16x32_bf16(
                        af[mi], bfr[ni], acc[mi][ni], 0, 0, 0);
        }
    };

    int nt = K / 64;
    stage(buf0, 0);
    for (int ti = 0; ti < nt; ti += 2) {
        stage(buf1, (ti + 1) * 64);
        asm volatile("s_waitcnt vmcnt(%0)" :: "n"(NL) : "memory");
        __builtin_amdgcn_s_barrier();
        __builtin_amdgcn_sched_barrier(0);
        compute(buf0);
        __builtin_amdgcn_sched_barrier(0);
        __builtin_amdgcn_s_barrier();
        if (ti + 2 < nt) {
            stage(buf0, (ti + 2) * 64);
            asm volatile("s_waitcnt vmcnt(%0)" :: "n"(NL) : "memory");
        } else {
            asm volatile("s_waitcnt vmcnt(0)" ::: "memory");
        }
        __builtin_amdgcn_s_barrier();
        __builtin_amdgcn_sched_barrier(0);
        compute(buf1);
        __builtin_amdgcn_sched_barrier(0);
        __builtin_amdgcn_s_barrier();
    }
}

// ============ megakernel args ============
struct MegaArgs {
    const int* ids; const int* mask;
    const float* wemb; const float* pemb; const float* emb_g; const float* emb_b;
    const u16* WqkvT; const u16* WoT; const u16* WiT; const u16* Wo2T;
    const float* bqkv; const float* bo; const float* bi; const float* bo2;
    const float* g1; const float* b1; const float* g2; const float* b2;
    const float* rW1; const float* rb1; const float* rW2; const float* rb2;
    const float* temp;
    const float* qA; const float* qB; const float* vA; const float* vB;
    const float* cW1; const float* cb1; const float* cW2; const float* cb2;
    float* h; float* h2; u16* h_bf; u16* o_bf; u16* qkv_bf; u16* ffb_bf; u16* vT;
    float* tq; float* tv; float* y1; int* task; float* out;
    unsigned* bar;
};

// ============ phase device functions ============
__device__ __forceinline__ void embed_row(
    const MegaArgs& a, int m, int t, volatile float* sb4) {
    int s = m & (SEQ - 1);
    int id = a.ids[m];
    float x[3];
    float sum = 0.f;
    #pragma unroll
    for (int j = 0; j < 3; ++j) {
        int d = t + j * 256;
        x[j] = a.wemb[(size_t)id * DIM + d] + a.pemb[(size_t)(s + 2) * DIM + d];
        sum += x[j];
    }
    float mean = block_sum256(sum, sb4) * (1.0f / DIM);
    float vs = 0.f;
    #pragma unroll
    for (int j = 0; j < 3; ++j) { float c = x[j] - mean; vs += c * c; }
    float var = block_sum256(vs, sb4) * (1.0f / DIM);
    float rstd = rsqrtf(var + 1e-5f);
    #pragma unroll
    for (int j = 0; j < 3; ++j) {
        int d = t + j * 256;
        float r = (x[j] - mean) * rstd * a.emb_g[d] + a.emb_b[d];
        a.h[(size_t)m * DIM + d] = r;
        a.h_bf[(size_t)m * DIM + d] = f2bf(r);
    }
}

__device__ __forceinline__ void add_ln_row(
    float* h, const float* proj, const float* g, const float* bb,
    u16* h_bf, int m, int t, volatile float* sb4) {
    float x[3];
    float sum = 0.f;
    #pragma unroll
    for (int j = 0; j < 3; ++j) {
        int d = t + j * 256;
        x[j] = h[(size_t)m * DIM + d] + proj[(size_t)m * DIM + d];
        sum += x[j];
    }
    float mean = block_sum256(sum, sb4) * (1.0f / DIM);
    float vs = 0.f;
    #pragma unroll
    for (int j = 0; j < 3; ++j) { float c = x[j] - mean; vs += c * c; }
    float var = block_sum256(vs, sb4) * (1.0f / DIM);
    float rstd = rsqrtf(var + 1e-5f);
    #pragma unroll
    for (int j = 0; j < 3; ++j) {
        int d = t + j * 256;
        float r = (x[j] - mean) * rstd * g[d] + bb[d];
        h[(size_t)m * DIM + d] = r;
        h_bf[(size_t)m * DIM + d] = f2bf(r);
    }
}

template<int BM, int BN, int ACT, int OUTMODE>   // OUTMODE: 0=f32, 1=bf16
__device__ __forceinline__ void gemm_tile(
    const u16* A, int lda, const u16* B, int ldb, const float* bias,
    float* Cf, u16* Cb, int ldc, int K, int m0, int n0, int t, u16* lds) {
    constexpr int FM = BM / 32, FN = BN / 32;
    floatx4 acc[FM][FN];
    gemm_core<BM, BN>(A, lda, B, ldb, K, m0, n0, lds, acc);
    int lane = t & 63, wave = t >> 6;
    int wr = wave >> 1, wc = wave & 1;
    int wm0 = wr * (BM / 2), wn0 = wc * (BN / 2);
    int cr = (lane >> 4) * 4, cc = lane & 15;
    #pragma unroll
    for (int mi = 0; mi < FM; ++mi) {
        #pragma unroll
        for (int ni = 0; ni < FN; ++ni) {
            int col = n0 + wn0 + ni * 16 + cc;
            float bsv = bias ? bias[col] : 0.f;
            #pragma unroll
            for (int j = 0; j < 4; ++j) {
                int row = m0 + wm0 + mi * 16 + cr + j;
                float r = acc[mi][ni][j] + bsv;
                if (ACT == 1) r = geluf(r);
                if (OUTMODE == 0) Cf[(size_t)row * ldc + col] = r;
                else Cb[(size_t)row * ldc + col] = f2bf(r);
            }
        }
    }
}

template<int LORA>
__device__ __forceinline__ void qkv_tile(
    const MegaArgs& a, const u16* Bw, const float* bias, int layer,
    int m0, int n0, int t, u16* lds) {
    floatx4 acc[4][4];
    gemm_core<128, 128>(a.h_bf, DIM, Bw, DIM, DIM, m0, n0, lds, acc);
    int lane = t & 63, wave = t >> 6;
    int wr = wave >> 1, wc = wave & 1;
    int wm0 = wr * 64, wn0 = wc * 64;
    int cr = (lane >> 4) * 4, cc = lane & 15;
    const float* tvec = nullptr;
    const float* Bmat = nullptr;
    if (LORA) {
        int tk = a.task[m0 >> 8];
        if (n0 < DIM) {
            tvec = a.tq;
            Bmat = a.qB + ((size_t)tk * LAYERS + layer) * DIM * LRANK;
        } else if (n0 >= 2 * DIM) {
            tvec = a.tv;
            Bmat = a.vB + ((size_t)tk * LAYERS + layer) * DIM * LRANK - (size_t)2 * DIM * LRANK;
        }
    }
    bool vrange = (n0 >= 2 * DIM);
    #pragma unroll
    for (int mi = 0; mi < 4; ++mi) {
        #pragma unroll
        for (int j = 0; j < 4; ++j) {
            int row = m0 + wm0 + mi * 16 + cr + j;
            float4 t0, t1, t2, t3;
            if (LORA && tvec) {
                const float* tp = tvec + (size_t)row * LRANK;
                t0 = *(const float4*)(tp + 0);  t1 = *(const float4*)(tp + 4);
                t2 = *(const float4*)(tp + 8);  t3 = *(const float4*)(tp + 12);
            }
            #pragma unroll
            for (int ni = 0; ni < 4; ++ni) {
                int col = n0 + wn0 + ni * 16 + cc;
                float r = acc[mi][ni][j] + bias[col];
                if (LORA && tvec) {
                    const float* bp = Bmat + (size_t)col * LRANK;
                    float4 b0 = *(const float4*)(bp + 0),  b1 = *(const float4*)(bp + 4);
                    float4 b2 = *(const float4*)(bp + 8),  b3 = *(const float4*)(bp + 12);
                    float d = t0.x * b0.x + t0.y * b0.y + t0.z * b0.z + t0.w * b0.w
                            + t1.x * b1.x + t1.y * b1.y + t1.z * b1.z + t1.w * b1.w
                            + t2.x * b2.x + t2.y * b2.y + t2.z * b2.z + t2.w * b2.w
                            + t3.x * b3.x + t3.y * b3.y + t3.z * b3.z + t3.w * b3.w;
                    r += LORA_SC * d;
                }
                u16 rb = f2bf(r);
                a.qkv_bf[(size_t)row * QKVLD + col] = rb;
                if (vrange) {
                    int vcol = col - 2 * DIM;
                    int hh = vcol >> 6, dd = vcol & 63;
                    int bb = row >> 8, kpos = row & 255;
                    a.vT[((size_t)(bb * NH + hh) * HDIM + dd) * SEQ + kpos] = rb;
                }
            }
        }
    }
}

// ---- fused attention unit ----
__device__ __forceinline__ int lds256_idx(int r, int col) {
    int sub = col >> 6, inner = col & 63;
    return r * 256 + sub * 64 + ((((inner >> 3) ^ (r & 7))) << 3) + (inner & 7);
}
__device__ __forceinline__ short8 frag_read256(const u16* base, int r, int kk, int kg) {
    int col = kk * 32 + kg * 8;
    int sub = col >> 6, slot = (col & 63) >> 3;
    return *(const short8*)(base + r * 256 + sub * 64 + ((slot ^ (r & 7)) << 3));
}

__device__ __forceinline__ void attn_unit(
    const MegaArgs& a, int qt, int z, int t, u16* lds) {
    u16* KV = lds;
    u16* P = lds + 256 * 64;
    int b = z / NH, h = z % NH;
    int lane = t & 63, w = t >> 6;
    int cc = lane & 15, q4 = lane >> 4;

    float mb[16];
    #pragma unroll
    for (int ni = 0; ni < 16; ++ni)
        mb[ni] = (1.0f - (float)a.mask[b * SEQ + ni * 16 + cc]) * -1e9f;

    int qrow = b * SEQ + qt * 64 + w * 16 + cc;
    const u16* qp = a.qkv_bf + (size_t)qrow * QKVLD + h * HDIM + q4 * 8;
    short8 qa0 = *(const short8*)(qp);
    short8 qa1 = *(const short8*)(qp + 32);

    stage_tile<256>(a.qkv_bf + (size_t)(b * SEQ) * QKVLD + DIM + h * HDIM, QKVLD, KV, w, lane);
    __syncthreads();

    floatx4 s[16];
    #pragma unroll
    for (int ni = 0; ni < 16; ++ni) s[ni] = (floatx4){0.f, 0.f, 0.f, 0.f};
    #pragma unroll
    for (int kk = 0; kk < 2; ++kk) {
        short8 qa = kk == 0 ? qa0 : qa1;
        #pragma unroll
        for (int ni = 0; ni < 16; ++ni) {
            short8 kf = frag_read(KV, ni * 16 + cc, kk * 4 + q4);
            s[ni] = __builtin_amdgcn_mfma_f32_16x16x32_bf16(qa, kf, s[ni], 0, 0, 0);
        }
    }

    float pv[16][4];
    float mrow[4] = {-1e30f, -1e30f, -1e30f, -1e30f};
    #pragma unroll
    for (int ni = 0; ni < 16; ++ni)
        #pragma unroll
        for (int j = 0; j < 4; ++j) {
            float v = s[ni][j] * 0.125f + mb[ni];
            pv[ni][j] = v;
            mrow[j] = fmaxf(mrow[j], v);
        }
    #pragma unroll
    for (int o = 1; o < 16; o <<= 1)
        #pragma unroll
        for (int j = 0; j < 4; ++j) mrow[j] = fmaxf(mrow[j], __shfl_xor(mrow[j], o));
    float srow[4] = {0.f, 0.f, 0.f, 0.f};
    #pragma unroll
    for (int ni = 0; ni < 16; ++ni)
        #pragma unroll
        for (int j = 0; j < 4; ++j) {
            float e = __expf(pv[ni][j] - mrow[j]);
            pv[ni][j] = e;
            srow[j] += e;
        }
    #pragma unroll
    for (int o = 1; o < 16; o <<= 1)
        #pragma unroll
        for (int j = 0; j < 4; ++j) srow[j] += __shfl_xor(srow[j], o);
    float inv[4];
    #pragma unroll
    for (int j = 0; j < 4; ++j) inv[j] = 1.0f / srow[j];

    u16* Pw = P + w * 16 * 256;
    #pragma unroll
    for (int ni = 0; ni < 16; ++ni)
        #pragma unroll
        for (int j = 0; j < 4; ++j)
            Pw[lds256_idx(q4 * 4 + j, ni * 16 + cc)] = f2bf(pv[ni][j] * inv[j]);
    __syncthreads();

    {
        const u16* vz = a.vT + (size_t)z * HDIM * SEQ;
        int rin = lane >> 3, slot = lane & 7;
        #pragma unroll
        for (int c0 = 0; c0 < 32; c0 += 4) {
            int c = c0 + w;
            int vrow = c * 8 + rin;
            int d = vrow >> 2, sub = vrow & 3;
            const u16* src = vz + d * 256 + sub * 64 + (((slot ^ (d & 7))) << 3);
            __builtin_amdgcn_global_load_lds(
                (const __attribute__((address_space(1))) unsigned int*)src,
                (__attribute__((address_space(3))) unsigned int*)(KV + c * 512 + lane * 8),
                16, 0, 0);
        }
    }
    __syncthreads();

    floatx4 oa[4];
    #pragma unroll
    for (int ni = 0; ni < 4; ++ni) oa[ni] = (floatx4){0.f, 0.f, 0.f, 0.f};
    #pragma unroll
    for (int kk = 0; kk < 8; ++kk) {
        short8 pf = frag_read256(Pw, cc, kk, q4);
        #pragma unroll
        for (int ni = 0; ni < 4; ++ni) {
            short8 vf = frag_read256(KV, ni * 16 + cc, kk, q4);
            oa[ni] = __builtin_amdgcn_mfma_f32_16x16x32_bf16(pf, vf, oa[ni], 0, 0, 0);
        }
    }
    #pragma unroll
    for (int ni = 0; ni < 4; ++ni)
        #pragma unroll
        for (int j = 0; j < 4; ++j) {
            int m = b * SEQ + qt * 64 + w * 16 + q4 * 4 + j;
            a.o_bf[(size_t)m * DIM + h * HDIM + ni * 16 + cc] = f2bf(oa[ni][j]);
        }
}

// ---- LoRA t-vectors unit ----
__device__ __forceinline__ void lora_t_unit(
    const MegaArgs& a, int layer, int u, int t) {
    int which = u & 1;
    const float* Ab = which ? a.vA : a.qA;
    float* tout = which ? a.tv : a.tq;
    int m0 = (u >> 1) * 64;
    int tk = a.task[m0 >> 8];
    const float* Ap = Ab + ((size_t)tk * LAYERS + layer) * LRANK * DIM;
    int row = t & 63, rb = t >> 6;
    float s[4] = {0.f, 0.f, 0.f, 0.f};
    const float* hrow = a.h + (size_t)(m0 + row) * DIM;
    for (int d = 0; d < DIM; d += 4) {
        float4 hv = *(const float4*)&hrow[d];
        #pragma unroll
        for (int i = 0; i < 4; ++i) {
            float4 av = *(const float4*)&Ap[(size_t)(rb + i * 4) * DIM + d];
            s[i] += hv.x * av.x + hv.y * av.y + hv.z * av.z + hv.w * av.w;
        }
    }
    #pragma unroll
    for (int i = 0; i < 4; ++i)
        tout[(size_t)(m0 + row) * LRANK + rb + i * 4] = s[i];
}

// ---- heads ----
template<int TANH>
__device__ __forceinline__ void head1_unit(
    const float* h, const float* W1base, const float* b1base,
    const int* taskp, float* y1, int u, int t, u16* lds) {
    int b = u / 12;
    int c0 = (u % 12) * 64;
    int tk = taskp ? taskp[b] : 0;
    const float* W1 = W1base + (size_t)tk * DIM * DIM;
    const float* b1 = b1base + (size_t)tk * DIM;
    float* cls = (float*)lds;
    float* part = cls + DIM;
    for (int j = t; j < DIM; j += 256) cls[j] = h[(size_t)(b * SEQ) * DIM + j];
    __syncthreads();
    int col = c0 + (t & 63);
    int seg = t >> 6;
    float s = 0.f;
    #pragma unroll 4
    for (int d = seg * 192; d < seg * 192 + 192; ++d)
        s += cls[d] * W1[(size_t)d * DIM + col];
    part[seg * 64 + (t & 63)] = s;
    __syncthreads();
    if (t < 64) {
        float r = part[t] + part[64 + t] + part[128 + t] + part[192 + t] + b1[c0 + t];
        y1[(size_t)b * DIM + c0 + t] = TANH ? tanhf(r) : fmaxf(r, 0.f);
    }
}

__device__ __forceinline__ void router_fin_unit(
    const MegaArgs& a, int b, int t, u16* lds) {
    float* red = (float*)lds;
    float p[3] = {0.f, 0.f, 0.f};
    #pragma unroll
    for (int j = 0; j < 3; ++j) {
        int col = t + j * 256;
        float y = a.y1[(size_t)b * DIM + col];
        p[0] += y * a.rW2[col * 3 + 0];
        p[1] += y * a.rW2[col * 3 + 1];
        p[2] += y * a.rW2[col * 3 + 2];
    }
    #pragma unroll
    for (int o = 32; o; o >>= 1) {
        p[0] += __shfl_down(p[0], o);
        p[1] += __shfl_down(p[1], o);
        p[2] += __shfl_down(p[2], o);
    }
    int w = t >> 6;
    if ((t & 63) == 0) { red[0 * 4 + w] = p[0]; red[1 * 4 + w] = p[1]; red[2 * 4 + w] = p[2]; }
    __syncthreads();
    if (t == 0) {
        float tt = fmaxf(a.temp[0], 0.05f);
        float l[3];
        #pragma unroll
        for (int c = 0; c < 3; ++c) {
            l[c] = (red[c * 4 + 0] + red[c * 4 + 1] + red[c * 4 + 2] + red[c * 4 + 3] + a.rb2[c]) / tt;
            a.out[b * 3 + c] = l[c];
        }
        int bt = 0; float bv = l[0];
        if (l[1] > bv) { bv = l[1]; bt = 1; }
        if (l[2] > bv) { bv = l[2]; bt = 2; }
        a.task[b] = bt;
    }
}

__device__ __forceinline__ void cls_fin_unit(
    const MegaArgs& a, int b, int t, u16* lds) {
    float* red = (float*)lds;
    int tk = a.task[b];
    const float* W2 = a.cW2 + (size_t)tk * DIM * 2;
    const float* b2 = a.cb2 + tk * 2;
    float p[2] = {0.f, 0.f};
    #pragma unroll
    for (int j = 0; j < 3; ++j) {
        int col = t + j * 256;
        float y = a.y1[(size_t)b * DIM + col];
        p[0] += y * W2[col * 2 + 0];
        p[1] += y * W2[col * 2 + 1];
    }
    #pragma unroll
    for (int o = 32; o; o >>= 1) {
        p[0] += __shfl_down(p[0], o);
        p[1] += __shfl_down(p[1], o);
    }
    int w = t >> 6;
    if ((t & 63) == 0) { red[0 * 4 + w] = p[0]; red[1 * 4 + w] = p[1]; }
    __syncthreads();
    if (t == 0) {
        #pragma unroll
        for (int c = 0; c < 2; ++c)
            a.out[BATCH * TASKS + b * 2 + c] =
                red[c * 4 + 0] + red[c * 4 + 1] + red[c * 4 + 2] + red[c * 4 + 3] + b2[c];
    }
}

// ============ the megakernel (plain launch + tree grid barrier) ============
template<int PASS>
__global__ __launch_bounds__(256, 2) void encoder_mega(MegaArgs a) {
    __shared__ __align__(16) u16 lds[32768];   // 64 KB union -> exactly 2 blocks/CU
    const int bid = blockIdx.x;
    const int t = threadIdx.x;
    volatile float* sb4 = (volatile float*)lds;
    unsigned gen = 0;
    unsigned* bar = a.bar;

    for (int m = bid; m < MTOK; m += GRID)
        embed_row(a, m, t, sb4);
    gsync(bar, ++gen, bid);

    for (int l = 0; l < LAYERS; ++l) {
        const u16* WqkvT_l = a.WqkvT + (size_t)l * QKVLD * DIM;
        const u16* WoT_l   = a.WoT   + (size_t)l * DIM * DIM;
        const u16* WiT_l   = a.WiT   + (size_t)l * FFDIM * DIM;
        const u16* Wo2T_l  = a.Wo2T  + (size_t)l * DIM * FFDIM;
        const float* bqkv_l = a.bqkv + (size_t)l * QKVLD;
        const float* bo_l  = a.bo  + (size_t)l * DIM;
        const float* bi_l  = a.bi  + (size_t)l * FFDIM;
        const float* bo2_l = a.bo2 + (size_t)l * DIM;
        const float* g1_l  = a.g1  + (size_t)l * DIM;
        const float* b1_l  = a.b1  + (size_t)l * DIM;
        const float* g2_l  = a.g2  + (size_t)l * DIM;
        const float* b2_l  = a.b2  + (size_t)l * DIM;

        if (PASS == 1) {
            for (int u = bid; u < 64; u += GRID)
                lora_t_unit(a, l, u, t);
            gsync(bar, ++gen, bid);
        }
        for (int u = bid; u < 288; u += GRID)
            qkv_tile<PASS>(a, WqkvT_l, bqkv_l, l, (u / 18) * 128, (u % 18) * 128, t, lds);
        gsync(bar, ++gen, bid);
        for (int u = bid; u < 384; u += GRID) {
            __syncthreads();
            attn_unit(a, u & 3, u >> 2, t, lds);
        }
        gsync(bar, ++gen, bid);
        for (int u = bid; u < 192; u += GRID)
            gemm_tile<64, 128, 0, 0>(a.o_bf, DIM, WoT_l, DIM, bo_l, a.h2, nullptr, DIM, DIM,
                                     (u / 6) * 64, (u % 6) * 128, t, lds);
        gsync(bar, ++gen, bid);
        for (int m = bid; m < MTOK; m += GRID)
            add_ln_row(a.h, a.h2, g1_l, b1_l, a.h_bf, m, t, sb4);
        gsync(bar, ++gen, bid);
        for (int u = bid; u < 384; u += GRID)
            gemm_tile<128, 128, 1, 1>(a.h_bf, DIM, WiT_l, DIM, bi_l, nullptr, a.ffb_bf, FFDIM, DIM,
                                      (u / 24) * 128, (u % 24) * 128, t, lds);
        gsync(bar, ++gen, bid);
        for (int u = bid; u < 192; u += GRID)
            gemm_tile<64, 128, 0, 0>(a.ffb_bf, FFDIM, Wo2T_l, FFDIM, bo2_l, a.h2, nullptr, DIM, FFDIM,
                                     (u / 6) * 64, (u % 6) * 128, t, lds);
        gsync(bar, ++gen, bid);
        for (int m = bid; m < MTOK; m += GRID)
            add_ln_row(a.h, a.h2, g2_l, b2_l, a.h_bf, m, t, sb4);
        gsync(bar, ++gen, bid);
    }

    if (PASS == 0) {
        for (int u = bid; u < 96; u += GRID) {
            __syncthreads();
            head1_unit<0>(a.h, a.rW1, a.rb1, nullptr, a.y1, u, t, lds);
        }
        gsync(bar, ++gen, bid);
        if (bid < BATCH)
            router_fin_unit(a, bid, t, lds);
    } else {
        for (int u = bid; u < 96; u += GRID) {
            __syncthreads();
            head1_unit<1>(a.h, a.cW1, a.cb1, a.task, a.y1, u, t, lds);
        }
        gsync(bar, ++gen, bid);
        if (bid < BATCH)
            cls_fin_unit(a, bid, t, lds);
    }
}

extern "C" void kernel_launch(void* const* d_in, const int* in_sizes, int n_in,
                              void* d_out, int out_size, void* d_ws, size_t ws_size,
                              hipStream_t stream) {
    (void)in_sizes; (void)n_in; (void)out_size; (void)ws_size;
    const int*   ids   = (const int*)d_in[0];
    const int*   mask  = (const int*)d_in[1];
    const float* wemb  = (const float*)d_in[2];
    const float* pemb  = (const float*)d_in[3];
    const float* emb_g = (const float*)d_in[4];
    const float* emb_b = (const float*)d_in[5];
    const float* Wq    = (const float*)d_in[6];
    const float* Wk    = (const float*)d_in[7];
    const float* Wv    = (const float*)d_in[8];
    const float* Wo    = (const float*)d_in[9];
    const float* Wi    = (const float*)d_in[10];
    const float* Wo2   = (const float*)d_in[11];
    const float* bq    = (const float*)d_in[12];
    const float* bk    = (const float*)d_in[13];
    const float* bv    = (const float*)d_in[14];
    const float* bo    = (const float*)d_in[15];
    const float* bi    = (const float*)d_in[16];
    const float* bo2   = (const float*)d_in[17];
    const float* g1    = (const float*)d_in[18];
    const float* b1    = (const float*)d_in[19];
    const float* g2    = (const float*)d_in[20];
    const float* b2    = (const float*)d_in[21];
    const float* rW1   = (const float*)d_in[22];
    const float* rb1   = (const float*)d_in[23];
    const float* rW2   = (const float*)d_in[24];
    const float* rb2   = (const float*)d_in[25];
    const float* temp  = (const float*)d_in[26];
    const float* qA    = (const float*)d_in[27];
    const float* qB    = (const float*)d_in[28];
    const float* vA    = (const float*)d_in[29];
    const float* vB    = (const float*)d_in[30];
    const float* cW1   = (const float*)d_in[31];
    const float* cb1   = (const float*)d_in[32];
    const float* cW2   = (const float*)d_in[33];
    const float* cb2   = (const float*)d_in[34];
    float* out = (float*)d_out;

    const size_t MD = (size_t)MTOK * DIM;
    char* p = (char*)d_ws;
    auto alloc = [&](size_t bytes) { char* r = p; p += (bytes + 255) & ~(size_t)255; return r; };
    float* h      = (float*)alloc(MD * 4);
    float* h2     = (float*)alloc(MD * 4);
    u16* h_bf   = (u16*)alloc(MD * 2);
    u16* o_bf   = (u16*)alloc(MD * 2);
    u16* qkv_bf = (u16*)alloc((size_t)MTOK * QKVLD * 2);
    u16* ffb_bf = (u16*)alloc((size_t)MTOK * FFDIM * 2);
    u16* vT     = (u16*)alloc((size_t)ZB * HDIM * SEQ * 2);
    float* tq   = (float*)alloc((size_t)MTOK * LRANK * 4);
    float* tv   = (float*)alloc((size_t)MTOK * LRANK * 4);
    float* bqkv = (float*)alloc((size_t)LAYERS * QKVLD * 4);
    float* y1   = (float*)alloc((size_t)BATCH * DIM * 4);
    int* task   = (int*)alloc(256);
    unsigned* barmem = (unsigned*)alloc(4096);   // 2 x 512-unsigned barrier regions
    u16* WqkvT  = (u16*)alloc((size_t)LAYERS * QKVLD * DIM * 2);
    u16* WoT    = (u16*)alloc((size_t)LAYERS * DIM * DIM * 2);
    u16* WiT    = (u16*)alloc((size_t)LAYERS * FFDIM * DIM * 2);
    u16* Wo2T   = (u16*)alloc((size_t)LAYERS * DIM * FFDIM * 2);

    hipMemsetAsync(barmem, 0, 4096, stream);

    dim3 blk(256);
    w_transpose64<<<dim3(12, 12, LAYERS), blk, 0, stream>>>(Wq, (size_t)DIM * DIM, WqkvT, (size_t)QKVLD * DIM, DIM, DIM, 0);
    w_transpose64<<<dim3(12, 12, LAYERS), blk, 0, stream>>>(Wk, (size_t)DIM * DIM, WqkvT, (size_t)QKVLD * DIM, DIM, DIM, DIM);
    w_transpose64<<<dim3(12, 12, LAYERS), blk, 0, stream>>>(Wv, (size_t)DIM * DIM, WqkvT, (size_t)QKVLD * DIM, DIM, DIM, 2 * DIM);
    w_transpose64<<<dim3(12, 12, LAYERS), blk, 0, stream>>>(Wo, (size_t)DIM * DIM, WoT, (size_t)DIM * DIM, DIM, DIM, 0);
    w_transpose64<<<dim3(48, 12, LAYERS), blk, 0, stream>>>(Wi, (size_t)DIM * FFDIM, WiT, (size_t)FFDIM * DIM, FFDIM, DIM, 0);
    w_transpose64<<<dim3(12, 48, LAYERS), blk, 0, stream>>>(Wo2, (size_t)FFDIM * DIM, Wo2T, (size_t)DIM * FFDIM, DIM, FFDIM, 0);
    build_bqkv<<<LAYERS, blk, 0, stream>>>(bq, bk, bv, bqkv);

    MegaArgs a;
    a.ids = ids; a.mask = mask; a.wemb = wemb; a.pemb = pemb;
    a.emb_g = emb_g; a.emb_b = emb_b;
    a.WqkvT = WqkvT; a.WoT = WoT; a.WiT = WiT; a.Wo2T = Wo2T;
    a.bqkv = bqkv; a.bo = bo; a.bi = bi; a.bo2 = bo2;
    a.g1 = g1; a.b1 = b1; a.g2 = g2; a.b2 = b2;
    a.rW1 = rW1; a.rb1 = rb1; a.rW2 = rW2; a.rb2 = rb2; a.temp = temp;
    a.qA = qA; a.qB = qB; a.vA = vA; a.vB = vB;
    a.cW1 = cW1; a.cb1 = cb1; a.cW2 = cW2; a.cb2 = cb2;
    a.h = h; a.h2 = h2; a.h_bf = h_bf; a.o_bf = o_bf;
    a.qkv_bf = qkv_bf; a.ffb_bf = ffb_bf; a.vT = vT;
    a.tq = tq; a.tv = tv; a.y1 = y1; a.task = task; a.out = out;

    a.bar = barmem;
    encoder_mega<0><<<dim3(GRID), blk, 0, stream>>>(a);
    a.bar = barmem + 512;
    encoder_mega<1><<<dim3(GRID), blk, 0, stream>>>(a);
}

// Round 9
// 3632.045 us; speedup vs baseline: 5.4437x; 2.4283x over previous
//
#include <hip/hip_runtime.h>
#include <math.h>

#define DIM 768
#define LAYERS 12
#define NH 12
#define HDIM 64
#define FFDIM 3072
#define SEQ 256
#define BATCH 8
#define MTOK (BATCH*SEQ)   // 2048
#define TASKS 3
#define LRANK 16
#define LORA_SC 2.0f
#define QKVLD 2304
#define ZB (BATCH*NH)      // 96

typedef unsigned short u16;
typedef __attribute__((ext_vector_type(8))) short short8;
typedef __attribute__((ext_vector_type(4))) float floatx4;
typedef __attribute__((ext_vector_type(4))) unsigned short u16x4;

__device__ __forceinline__ u16 f2bf(float f) {
    unsigned int u = __float_as_uint(f);
    u = (u + 0x7fff + ((u >> 16) & 1)) >> 16;
    return (u16)u;
}
__device__ __forceinline__ float bf2f(u16 v) {
    return __uint_as_float(((unsigned)v) << 16);
}

__device__ __forceinline__ float geluf(float x) {
    float u = 0.7978845608028654f * (x + 0.044715f * x * x * x);
    u = fminf(fmaxf(u, -15.f), 15.f);
    float e = __expf(2.f * u);
    float th = (e - 1.f) / (e + 1.f);
    return 0.5f * x * (1.f + th);
}

__device__ __forceinline__ float block_sum256(float v, volatile float* sb4) {
    #pragma unroll
    for (int o = 32; o; o >>= 1) v += __shfl_down(v, o);
    int w = threadIdx.x >> 6;
    if ((threadIdx.x & 63) == 0) sb4[w] = v;
    __syncthreads();
    float total = sb4[0] + sb4[1] + sb4[2] + sb4[3];
    __syncthreads();
    return total;
}

// XCD-aware bijective block swizzle (nwg divisible by 8 at all call sites)
__device__ __forceinline__ void xcd_map(int* bx, int* by) {
    int gx = gridDim.x;
    int nwg = gx * gridDim.y;
    int orig = blockIdx.y * gx + blockIdx.x;
    int swz = (orig & 7) * (nwg >> 3) + (orig >> 3);
    *bx = swz % gx; *by = swz / gx;
}

// ============ weight transpose fp32 [K][N] -> bf16 [row_off+N][K], 64x64 ============
__global__ __launch_bounds__(256) void w_transpose64(
    const float* __restrict__ src, size_t src_ls,
    u16* __restrict__ dst, size_t dst_ls, int N, int dstld, int row_off) {
    __shared__ float tile[64][65];
    int l = blockIdx.z;
    int k0 = blockIdx.y * 64, n0 = blockIdx.x * 64;
    int t = threadIdx.x;
    int r = t >> 4, c4 = (t & 15) * 4;
    const float* s = src + (size_t)l * src_ls + (size_t)k0 * N + n0;
    #pragma unroll
    for (int i = 0; i < 4; ++i) {
        float4 v = *(const float4*)&s[(size_t)(r + i * 16) * N + c4];
        tile[r + i * 16][c4 + 0] = v.x; tile[r + i * 16][c4 + 1] = v.y;
        tile[r + i * 16][c4 + 2] = v.z; tile[r + i * 16][c4 + 3] = v.w;
    }
    __syncthreads();
    u16* d = dst + (size_t)l * dst_ls;
    #pragma unroll
    for (int i = 0; i < 4; ++i) {
        int n = r + i * 16;
        u16x4 o;
        o[0] = f2bf(tile[c4 + 0][n]); o[1] = f2bf(tile[c4 + 1][n]);
        o[2] = f2bf(tile[c4 + 2][n]); o[3] = f2bf(tile[c4 + 3][n]);
        *(u16x4*)&d[(size_t)(row_off + n0 + n) * dstld + k0 + c4] = o;
    }
}

__global__ __launch_bounds__(256) void build_bqkv(
    const float* __restrict__ bq, const float* __restrict__ bk,
    const float* __restrict__ bv, float* __restrict__ bqkv) {
    int l = blockIdx.x;
    for (int i = threadIdx.x; i < QKVLD; i += 256) {
        float v = i < DIM ? bq[l * DIM + i]
                : (i < 2 * DIM ? bk[l * DIM + i - DIM] : bv[l * DIM + i - 2 * DIM]);
        bqkv[(size_t)l * QKVLD + i] = v;
    }
}

// ============ embedding + LN (fp32 + bf16 out) ============
__global__ __launch_bounds__(256) void embed_ln_kernel(
    const int* __restrict__ ids, const float* __restrict__ wemb,
    const float* __restrict__ pemb, const float* __restrict__ g,
    const float* __restrict__ bb, float* __restrict__ out, u16* __restrict__ out_bf) {
    __shared__ float sb[4];
    int m = blockIdx.x;
    int s = m & (SEQ - 1);
    int id = ids[m];
    int t = threadIdx.x;
    float x[3];
    float sum = 0.f;
    #pragma unroll
    for (int j = 0; j < 3; ++j) {
        int d = t + j * 256;
        x[j] = wemb[(size_t)id * DIM + d] + pemb[(size_t)(s + 2) * DIM + d];
        sum += x[j];
    }
    float mean = block_sum256(sum, sb) * (1.0f / DIM);
    float vs = 0.f;
    #pragma unroll
    for (int j = 0; j < 3; ++j) { float c = x[j] - mean; vs += c * c; }
    float var = block_sum256(vs, sb) * (1.0f / DIM);
    float rstd = rsqrtf(var + 1e-5f);
    #pragma unroll
    for (int j = 0; j < 3; ++j) {
        int d = t + j * 256;
        float r = (x[j] - mean) * rstd * g[d] + bb[d];
        out[(size_t)m * DIM + d] = r;
        out_bf[(size_t)m * DIM + d] = f2bf(r);
    }
}

// ============ residual add (bf16 proj) + LN in place, + bf16 out ============
__global__ __launch_bounds__(256) void add_ln_kernel(
    float* __restrict__ h, const u16* __restrict__ proj,
    const float* __restrict__ g, const float* __restrict__ bb, u16* __restrict__ h_bf) {
    __shared__ float sb[4];
    int m = blockIdx.x;
    int t = threadIdx.x;
    float x[3];
    float sum = 0.f;
    #pragma unroll
    for (int j = 0; j < 3; ++j) {
        int d = t + j * 256;
        x[j] = h[(size_t)m * DIM + d] + bf2f(proj[(size_t)m * DIM + d]);
        sum += x[j];
    }
    float mean = block_sum256(sum, sb) * (1.0f / DIM);
    float vs = 0.f;
    #pragma unroll
    for (int j = 0; j < 3; ++j) { float c = x[j] - mean; vs += c * c; }
    float var = block_sum256(vs, sb) * (1.0f / DIM);
    float rstd = rsqrtf(var + 1e-5f);
    #pragma unroll
    for (int j = 0; j < 3; ++j) {
        int d = t + j * 256;
        float r = (x[j] - mean) * rstd * g[d] + bb[d];
        h[(size_t)m * DIM + d] = r;
        h_bf[(size_t)m * DIM + d] = f2bf(r);
    }
}

// ============ MFMA GEMM core (double-buffered, counted vmcnt) ============
template<int ROWS>
__device__ __forceinline__ void stage_tile(const u16* srcbase, int ldk,
                                           u16* ldsbase, int wave, int lane) {
    int rin = lane >> 3, slot = lane & 7;
    #pragma unroll
    for (int c0 = 0; c0 < ROWS / 8; c0 += 4) {
        int c = c0 + wave;
        int r = c * 8 + rin;
        int scol = ((slot ^ (r & 7)) << 3);
        const u16* src = srcbase + (size_t)r * ldk + scol;
        __builtin_amdgcn_global_load_lds(
            (const __attribute__((address_space(1))) unsigned int*)src,
            (__attribute__((address_space(3))) unsigned int*)(ldsbase + (size_t)c * 512 + lane * 8),
            16, 0, 0);
    }
}

__device__ __forceinline__ short8 frag_read(const u16* ldsbase, int r, int s) {
    return *(const short8*)(ldsbase + r * 64 + (((s ^ (r & 7)) << 3)));
}

// K/64 must be EVEN at all call sites (K=768 -> 12, K=3072 -> 48).
template<int BM, int BN>
__device__ __forceinline__ void gemm_core(
    const u16* __restrict__ A, int lda, const u16* __restrict__ B, int ldb,
    int K, int m0, int n0, u16* lds, floatx4 (&acc)[BM / 32][BN / 32]) {
    constexpr int TILE = (BM + BN) * 64;
    constexpr int NL = BM / 32 + BN / 32;
    u16* buf0 = lds;
    u16* buf1 = lds + TILE;
    int t = threadIdx.x, lane = t & 63, wave = t >> 6;
    int wr = wave >> 1, wc = wave & 1;
    constexpr int FM = BM / 32, FN = BN / 32;
    int wm0 = wr * (BM / 2), wn0 = wc * (BN / 2);
    #pragma unroll
    for (int i = 0; i < FM; ++i)
        #pragma unroll
        for (int j = 0; j < FN; ++j)
            acc[i][j] = (floatx4){0.f, 0.f, 0.f, 0.f};
    int lr = lane & 15, kg = lane >> 4;
    const u16* Abase = A + (size_t)m0 * lda;
    const u16* Bbase = B + (size_t)n0 * ldb;

    auto stage = [&](u16* dst, int k0) {
        stage_tile<BM>(Abase + k0, lda, dst, wave, lane);
        stage_tile<BN>(Bbase + k0, ldb, dst + BM * 64, wave, lane);
    };
    auto compute = [&](const u16* buf) {
        const u16* As = buf;
        const u16* Bs = buf + BM * 64;
        #pragma unroll
        for (int kk = 0; kk < 2; ++kk) {
            short8 af[FM], bfr[FN];
            #pragma unroll
            for (int mi = 0; mi < FM; ++mi)
                af[mi] = frag_read(As, wm0 + mi * 16 + lr, kk * 4 + kg);
            #pragma unroll
            for (int ni = 0; ni < FN; ++ni)
                bfr[ni] = frag_read(Bs, wn0 + ni * 16 + lr, kk * 4 + kg);
            #pragma unroll
            for (int mi = 0; mi < FM; ++mi)
                #pragma unroll
                for (int ni = 0; ni < FN; ++ni)
                    acc[mi][ni] = __builtin_amdgcn_mfma_f32_16x16x32_bf16(
                        af[mi], bfr[ni], acc[mi][ni], 0, 0, 0);
        }
    };

    int nt = K / 64;
    stage(buf0, 0);
    for (int ti = 0; ti < nt; ti += 2) {
        stage(buf1, (ti + 1) * 64);
        asm volatile("s_waitcnt vmcnt(%0)" :: "n"(NL) : "memory");
        __builtin_amdgcn_s_barrier();
        __builtin_amdgcn_sched_barrier(0);
        compute(buf0);
        __builtin_amdgcn_sched_barrier(0);
        __builtin_amdgcn_s_barrier();
        if (ti + 2 < nt) {
            stage(buf0, (ti + 2) * 64);
            asm volatile("s_waitcnt vmcnt(%0)" :: "n"(NL) : "memory");
        } else {
            asm volatile("s_waitcnt vmcnt(0)" ::: "memory");
        }
        __builtin_amdgcn_s_barrier();
        __builtin_amdgcn_sched_barrier(0);
        compute(buf1);
        __builtin_amdgcn_sched_barrier(0);
        __builtin_amdgcn_s_barrier();
    }
}

// ---- standard GEMM kernel ----
template<int BM, int BN, int ACT, int OUTMODE>   // OUTMODE: 0=f32, 1=bf16
__global__ __launch_bounds__(256) void gemm_mfma(
    const u16* __restrict__ A, int lda, const u16* __restrict__ B, int ldb,
    const float* __restrict__ bias, float* __restrict__ Cf, u16* __restrict__ Cb,
    int ldc, int K) {
    __shared__ u16 lds[2 * (BM + BN) * 64];
    constexpr int FM = BM / 32, FN = BN / 32;
    floatx4 acc[FM][FN];
    int bx, by;
    xcd_map(&bx, &by);
    int m0 = by * BM, n0 = bx * BN;
    gemm_core<BM, BN>(A, lda, B, ldb, K, m0, n0, lds, acc);
    int t = threadIdx.x, lane = t & 63, wave = t >> 6;
    int wr = wave >> 1, wc = wave & 1;
    int wm0 = wr * (BM / 2), wn0 = wc * (BN / 2);
    int cr = (lane >> 4) * 4, cc = lane & 15;
    #pragma unroll
    for (int mi = 0; mi < FM; ++mi) {
        #pragma unroll
        for (int ni = 0; ni < FN; ++ni) {
            int col = n0 + wn0 + ni * 16 + cc;
            float bsv = bias ? bias[col] : 0.f;
            #pragma unroll
            for (int j = 0; j < 4; ++j) {
                int row = m0 + wm0 + mi * 16 + cr + j;
                float r = acc[mi][ni][j] + bsv;
                if (ACT == 1) r = geluf(r);
                if (OUTMODE == 0) Cf[(size_t)row * ldc + col] = r;
                else Cb[(size_t)row * ldc + col] = f2bf(r);
            }
        }
    }
}

// ---- QKV GEMM: bias, optional fused LoRA, bf16 out, fused vT scatter ----
template<int LORA>
__global__ __launch_bounds__(256) void gemm_qkv(
    const u16* __restrict__ A, const u16* __restrict__ Bw,
    const float* __restrict__ bias, u16* __restrict__ qkv_bf,
    u16* __restrict__ vT,
    const float* __restrict__ tq, const float* __restrict__ tv,
    const float* __restrict__ qBb, const float* __restrict__ vBb,
    const int* __restrict__ taskp, int layer) {
    __shared__ u16 lds[2 * (128 + 128) * 64];
    floatx4 acc[4][4];
    int bx, by;
    xcd_map(&bx, &by);
    int m0 = by * 128, n0 = bx * 128;
    gemm_core<128, 128>(A, DIM, Bw, DIM, DIM, m0, n0, lds, acc);
    int t = threadIdx.x, lane = t & 63, wave = t >> 6;
    int wr = wave >> 1, wc = wave & 1;
    int wm0 = wr * 64, wn0 = wc * 64;
    int cr = (lane >> 4) * 4, cc = lane & 15;
    const float* tvec = nullptr;
    const float* Bmat = nullptr;
    if (LORA) {
        int tk = taskp[m0 >> 8];
        if (n0 < DIM) {
            tvec = tq;
            Bmat = qBb + ((size_t)tk * LAYERS + layer) * DIM * LRANK;
        } else if (n0 >= 2 * DIM) {
            tvec = tv;
            Bmat = vBb + ((size_t)tk * LAYERS + layer) * DIM * LRANK - (size_t)2 * DIM * LRANK;
        }
    }
    bool vrange = (n0 >= 2 * DIM);
    #pragma unroll
    for (int mi = 0; mi < 4; ++mi) {
        #pragma unroll
        for (int j = 0; j < 4; ++j) {
            int row = m0 + wm0 + mi * 16 + cr + j;
            float4 t0, t1, t2, t3;
            if (LORA && tvec) {
                const float* tp = tvec + (size_t)row * LRANK;
                t0 = *(const float4*)(tp + 0);  t1 = *(const float4*)(tp + 4);
                t2 = *(const float4*)(tp + 8);  t3 = *(const float4*)(tp + 12);
            }
            #pragma unroll
            for (int ni = 0; ni < 4; ++ni) {
                int col = n0 + wn0 + ni * 16 + cc;
                float r = acc[mi][ni][j] + bias[col];
                if (LORA && tvec) {
                    const float* bp = Bmat + (size_t)col * LRANK;
                    float4 b0 = *(const float4*)(bp + 0),  b1 = *(const float4*)(bp + 4);
                    float4 b2 = *(const float4*)(bp + 8),  b3 = *(const float4*)(bp + 12);
                    float d = t0.x * b0.x + t0.y * b0.y + t0.z * b0.z + t0.w * b0.w
                            + t1.x * b1.x + t1.y * b1.y + t1.z * b1.z + t1.w * b1.w
                            + t2.x * b2.x + t2.y * b2.y + t2.z * b2.z + t2.w * b2.w
                            + t3.x * b3.x + t3.y * b3.y + t3.z * b3.z + t3.w * b3.w;
                    r += LORA_SC * d;
                }
                u16 rb = f2bf(r);
                qkv_bf[(size_t)row * QKVLD + col] = rb;
                if (vrange) {
                    int vcol = col - 2 * DIM;
                    int hh = vcol >> 6, dd = vcol & 63;
                    int bb = row >> 8, kpos = row & 255;
                    vT[((size_t)(bb * NH + hh) * HDIM + dd) * SEQ + kpos] = rb;
                }
            }
        }
    }
}

// ============ fused attention (1D grid, XCD-pinned: batch b -> XCD b) ============
__device__ __forceinline__ int lds256_idx(int r, int col) {
    int sub = col >> 6, inner = col & 63;
    return r * 256 + sub * 64 + ((((inner >> 3) ^ (r & 7))) << 3) + (inner & 7);
}
__device__ __forceinline__ short8 frag_read256(const u16* base, int r, int kk, int kg) {
    int col = kk * 32 + kg * 8;
    int sub = col >> 6, slot = (col & 63) >> 3;
    return *(const short8*)(base + r * 256 + sub * 64 + ((slot ^ (r & 7)) << 3));
}

__global__ __launch_bounds__(256) void attn_fused(
    const u16* __restrict__ qkv_bf, const u16* __restrict__ vT,
    const int* __restrict__ mask, u16* __restrict__ o_bf) {
    __shared__ u16 lds[256 * 64 + 64 * 256];
    u16* KV = lds;
    u16* P = lds + 256 * 64;
    // 384 blocks: i%8 = XCD heuristic; z = (i%8)*12 + (i>>3)/4 -> batch = z/12 = i%8
    int i = blockIdx.x;
    int xg = i & 7, j2 = i >> 3;
    int z = xg * 12 + (j2 >> 2);
    int qt = j2 & 3;
    int b = z / NH, h = z % NH;
    int t = threadIdx.x, lane = t & 63, w = t >> 6;
    int cc = lane & 15, q4 = lane >> 4;

    float mb[16];
    #pragma unroll
    for (int ni = 0; ni < 16; ++ni)
        mb[ni] = (1.0f - (float)mask[b * SEQ + ni * 16 + cc]) * -1e9f;

    int qrow = b * SEQ + qt * 64 + w * 16 + cc;
    const u16* qp = qkv_bf + (size_t)qrow * QKVLD + h * HDIM + q4 * 8;
    short8 qa0 = *(const short8*)(qp);
    short8 qa1 = *(const short8*)(qp + 32);

    stage_tile<256>(qkv_bf + (size_t)(b * SEQ) * QKVLD + DIM + h * HDIM, QKVLD, KV, w, lane);
    __syncthreads();

    floatx4 s[16];
    #pragma unroll
    for (int ni = 0; ni < 16; ++ni) s[ni] = (floatx4){0.f, 0.f, 0.f, 0.f};
    #pragma unroll
    for (int kk = 0; kk < 2; ++kk) {
        short8 qa = kk == 0 ? qa0 : qa1;
        #pragma unroll
        for (int ni = 0; ni < 16; ++ni) {
            short8 kf = frag_read(KV, ni * 16 + cc, kk * 4 + q4);
            s[ni] = __builtin_amdgcn_mfma_f32_16x16x32_bf16(qa, kf, s[ni], 0, 0, 0);
        }
    }

    float pv[16][4];
    float mrow[4] = {-1e30f, -1e30f, -1e30f, -1e30f};
    #pragma unroll
    for (int ni = 0; ni < 16; ++ni)
        #pragma unroll
        for (int j = 0; j < 4; ++j) {
            float v = s[ni][j] * 0.125f + mb[ni];
            pv[ni][j] = v;
            mrow[j] = fmaxf(mrow[j], v);
        }
    #pragma unroll
    for (int o = 1; o < 16; o <<= 1)
        #pragma unroll
        for (int j = 0; j < 4; ++j) mrow[j] = fmaxf(mrow[j], __shfl_xor(mrow[j], o));
    float srow[4] = {0.f, 0.f, 0.f, 0.f};
    #pragma unroll
    for (int ni = 0; ni < 16; ++ni)
        #pragma unroll
        for (int j = 0; j < 4; ++j) {
            float e = __expf(pv[ni][j] - mrow[j]);
            pv[ni][j] = e;
            srow[j] += e;
        }
    #pragma unroll
    for (int o = 1; o < 16; o <<= 1)
        #pragma unroll
        for (int j = 0; j < 4; ++j) srow[j] += __shfl_xor(srow[j], o);
    float inv[4];
    #pragma unroll
    for (int j = 0; j < 4; ++j) inv[j] = 1.0f / srow[j];

    u16* Pw = P + w * 16 * 256;
    #pragma unroll
    for (int ni = 0; ni < 16; ++ni)
        #pragma unroll
        for (int j = 0; j < 4; ++j)
            Pw[lds256_idx(q4 * 4 + j, ni * 16 + cc)] = f2bf(pv[ni][j] * inv[j]);
    __syncthreads();

    {
        const u16* vz = vT + (size_t)z * HDIM * SEQ;
        int rin = lane >> 3, slot = lane & 7;
        #pragma unroll
        for (int c0 = 0; c0 < 32; c0 += 4) {
            int c = c0 + w;
            int vrow = c * 8 + rin;
            int d = vrow >> 2, sub = vrow & 3;
            const u16* src = vz + d * 256 + sub * 64 + (((slot ^ (d & 7))) << 3);
            __builtin_amdgcn_global_load_lds(
                (const __attribute__((address_space(1))) unsigned int*)src,
                (__attribute__((address_space(3))) unsigned int*)(KV + c * 512 + lane * 8),
                16, 0, 0);
        }
    }
    __syncthreads();

    floatx4 oa[4];
    #pragma unroll
    for (int ni = 0; ni < 4; ++ni) oa[ni] = (floatx4){0.f, 0.f, 0.f, 0.f};
    #pragma unroll
    for (int kk = 0; kk < 8; ++kk) {
        short8 pf = frag_read256(Pw, cc, kk, q4);
        #pragma unroll
        for (int ni = 0; ni < 4; ++ni) {
            short8 vf = frag_read256(KV, ni * 16 + cc, kk, q4);
            oa[ni] = __builtin_amdgcn_mfma_f32_16x16x32_bf16(pf, vf, oa[ni], 0, 0, 0);
        }
    }
    #pragma unroll
    for (int ni = 0; ni < 4; ++ni)
        #pragma unroll
        for (int j = 0; j < 4; ++j) {
            int m = b * SEQ + qt * 64 + w * 16 + q4 * 4 + j;
            o_bf[(size_t)m * DIM + h * HDIM + ni * 16 + cc] = f2bf(oa[ni][j]);
        }
}

// ============ LoRA t-vectors ============
__global__ __launch_bounds__(256) void lora_t_kernel(
    const float* __restrict__ h, const float* __restrict__ qA,
    const float* __restrict__ vA, const int* __restrict__ task,
    int layer, float* __restrict__ tq, float* __restrict__ tv) {
    int which = blockIdx.y;
    const float* Ab = which ? vA : qA;
    float* tout = which ? tv : tq;
    int m0 = blockIdx.x * 64;
    int tk = task[m0 >> 8];
    const float* Ap = Ab + ((size_t)tk * LAYERS + layer) * LRANK * DIM;
    int t = threadIdx.x;
    int row = t & 63, rb = t >> 6;
    float s[4] = {0.f, 0.f, 0.f, 0.f};
    const float* hrow = h + (size_t)(m0 + row) * DIM;
    for (int d = 0; d < DIM; d += 4) {
        float4 hv = *(const float4*)&hrow[d];
        #pragma unroll
        for (int i = 0; i < 4; ++i) {
            float4 av = *(const float4*)&Ap[(size_t)(rb + i * 4) * DIM + d];
            s[i] += hv.x * av.x + hv.y * av.y + hv.z * av.z + hv.w * av.w;
        }
    }
    #pragma unroll
    for (int i = 0; i < 4; ++i)
        tout[(size_t)(m0 + row) * LRANK + rb + i * 4] = s[i];
}

// ============ heads: stage 1 (parallel matvec y1 = act(cls@W1+b1)) ============
template<int TANH>
__global__ __launch_bounds__(256) void head1_kernel(
    const float* __restrict__ h, const float* __restrict__ W1base,
    const float* __restrict__ b1base, const int* __restrict__ taskp,
    float* __restrict__ y1) {
    int b = blockIdx.y;
    int c0 = blockIdx.x * 64;
    int tk = taskp ? taskp[b] : 0;
    const float* W1 = W1base + (size_t)tk * DIM * DIM;
    const float* b1 = b1base + (size_t)tk * DIM;
    __shared__ float cls[DIM];
    __shared__ float part[4][64];
    int t = threadIdx.x;
    for (int j = t; j < DIM; j += 256) cls[j] = h[(size_t)(b * SEQ) * DIM + j];
    __syncthreads();
    int col = c0 + (t & 63);
    int seg = t >> 6;
    float s = 0.f;
    #pragma unroll 4
    for (int d = seg * 192; d < seg * 192 + 192; ++d)
        s += cls[d] * W1[(size_t)d * DIM + col];
    part[seg][t & 63] = s;
    __syncthreads();
    if (t < 64) {
        float r = part[0][t] + part[1][t] + part[2][t] + part[3][t] + b1[c0 + t];
        y1[(size_t)b * DIM + c0 + t] = TANH ? tanhf(r) : fmaxf(r, 0.f);
    }
}

// ============ router finalize ============
__global__ __launch_bounds__(256) void router_fin(
    const float* __restrict__ y1, const float* __restrict__ W2,
    const float* __restrict__ b2, const float* __restrict__ temp,
    float* __restrict__ out_logits, int* __restrict__ task) {
    int b = blockIdx.x;
    int t = threadIdx.x;
    __shared__ float red[3][4];
    float p[3] = {0.f, 0.f, 0.f};
    #pragma unroll
    for (int j = 0; j < 3; ++j) {
        int col = t + j * 256;
        float y = y1[(size_t)b * DIM + col];
        p[0] += y * W2[col * 3 + 0];
        p[1] += y * W2[col * 3 + 1];
        p[2] += y * W2[col * 3 + 2];
    }
    #pragma unroll
    for (int o = 32; o; o >>= 1) {
        p[0] += __shfl_down(p[0], o);
        p[1] += __shfl_down(p[1], o);
        p[2] += __shfl_down(p[2], o);
    }
    int w = t >> 6;
    if ((t & 63) == 0) { red[0][w] = p[0]; red[1][w] = p[1]; red[2][w] = p[2]; }
    __syncthreads();
    if (t == 0) {
        float tt = fmaxf(temp[0], 0.05f);
        float l[3];
        #pragma unroll
        for (int c = 0; c < 3; ++c) {
            l[c] = (red[c][0] + red[c][1] + red[c][2] + red[c][3] + b2[c]) / tt;
            out_logits[b * 3 + c] = l[c];
        }
        int bt = 0; float bv = l[0];
        if (l[1] > bv) { bv = l[1]; bt = 1; }
        if (l[2] > bv) { bv = l[2]; bt = 2; }
        task[b] = bt;
    }
}

// ============ classifier finalize ============
__global__ __launch_bounds__(256) void cls_fin(
    const float* __restrict__ y1, const float* __restrict__ cW2,
    const float* __restrict__ cb2, const int* __restrict__ task,
    float* __restrict__ out) {
    int b = blockIdx.x;
    int t = threadIdx.x;
    int tk = task[b];
    const float* W2 = cW2 + (size_t)tk * DIM * 2;
    const float* b2 = cb2 + tk * 2;
    __shared__ float red[2][4];
    float p[2] = {0.f, 0.f};
    #pragma unroll
    for (int j = 0; j < 3; ++j) {
        int col = t + j * 256;
        float y = y1[(size_t)b * DIM + col];
        p[0] += y * W2[col * 2 + 0];
        p[1] += y * W2[col * 2 + 1];
    }
    #pragma unroll
    for (int o = 32; o; o >>= 1) {
        p[0] += __shfl_down(p[0], o);
        p[1] += __shfl_down(p[1], o);
    }
    int w = t >> 6;
    if ((t & 63) == 0) { red[0][w] = p[0]; red[1][w] = p[1]; }
    __syncthreads();
    if (t == 0) {
        #pragma unroll
        for (int c = 0; c < 2; ++c)
            out[b * 2 + c] = red[c][0] + red[c][1] + red[c][2] + red[c][3] + b2[c];
    }
}

extern "C" void kernel_launch(void* const* d_in, const int* in_sizes, int n_in,
                              void* d_out, int out_size, void* d_ws, size_t ws_size,
                              hipStream_t stream) {
    (void)in_sizes; (void)n_in; (void)out_size; (void)ws_size;
    const int*   ids   = (const int*)d_in[0];
    const int*   mask  = (const int*)d_in[1];
    const float* wemb  = (const float*)d_in[2];
    const float* pemb  = (const float*)d_in[3];
    const float* emb_g = (const float*)d_in[4];
    const float* emb_b = (const float*)d_in[5];
    const float* Wq    = (const float*)d_in[6];
    const float* Wk    = (const float*)d_in[7];
    const float* Wv    = (const float*)d_in[8];
    const float* Wo    = (const float*)d_in[9];
    const float* Wi    = (const float*)d_in[10];
    const float* Wo2   = (const float*)d_in[11];
    const float* bq    = (const float*)d_in[12];
    const float* bk    = (const float*)d_in[13];
    const float* bv    = (const float*)d_in[14];
    const float* bo    = (const float*)d_in[15];
    const float* bi    = (const float*)d_in[16];
    const float* bo2   = (const float*)d_in[17];
    const float* g1    = (const float*)d_in[18];
    const float* b1    = (const float*)d_in[19];
    const float* g2    = (const float*)d_in[20];
    const float* b2    = (const float*)d_in[21];
    const float* rW1   = (const float*)d_in[22];
    const float* rb1   = (const float*)d_in[23];
    const float* rW2   = (const float*)d_in[24];
    const float* rb2   = (const float*)d_in[25];
    const float* temp  = (const float*)d_in[26];
    const float* qA    = (const float*)d_in[27];
    const float* qB    = (const float*)d_in[28];
    const float* vA    = (const float*)d_in[29];
    const float* vB    = (const float*)d_in[30];
    const float* cW1   = (const float*)d_in[31];
    const float* cb1   = (const float*)d_in[32];
    const float* cW2   = (const float*)d_in[33];
    const float* cb2   = (const float*)d_in[34];
    float* out = (float*)d_out;

    const size_t MD = (size_t)MTOK * DIM;
    char* p = (char*)d_ws;
    auto alloc = [&](size_t bytes) { char* r = p; p += (bytes + 255) & ~(size_t)255; return r; };
    float* h      = (float*)alloc(MD * 4);
    u16* h2b    = (u16*)alloc(MD * 2);
    u16* h_bf   = (u16*)alloc(MD * 2);
    u16* o_bf   = (u16*)alloc(MD * 2);
    u16* qkv_bf = (u16*)alloc((size_t)MTOK * QKVLD * 2);
    u16* ffb_bf = (u16*)alloc((size_t)MTOK * FFDIM * 2);
    u16* vT     = (u16*)alloc((size_t)ZB * HDIM * SEQ * 2);
    float* tq   = (float*)alloc((size_t)MTOK * LRANK * 4);
    float* tv   = (float*)alloc((size_t)MTOK * LRANK * 4);
    float* bqkv = (float*)alloc((size_t)LAYERS * QKVLD * 4);
    float* y1   = (float*)alloc((size_t)BATCH * DIM * 4);
    int* task   = (int*)alloc(256);
    u16* WqkvT  = (u16*)alloc((size_t)LAYERS * QKVLD * DIM * 2);
    u16* WoT    = (u16*)alloc((size_t)LAYERS * DIM * DIM * 2);
    u16* WiT    = (u16*)alloc((size_t)LAYERS * FFDIM * DIM * 2);
    u16* Wo2T   = (u16*)alloc((size_t)LAYERS * DIM * FFDIM * 2);

    dim3 blk(256);
    // --- weight prep (bf16, [N][K]) ---
    w_transpose64<<<dim3(12, 12, LAYERS), blk, 0, stream>>>(Wq, (size_t)DIM * DIM, WqkvT, (size_t)QKVLD * DIM, DIM, DIM, 0);
    w_transpose64<<<dim3(12, 12, LAYERS), blk, 0, stream>>>(Wk, (size_t)DIM * DIM, WqkvT, (size_t)QKVLD * DIM, DIM, DIM, DIM);
    w_transpose64<<<dim3(12, 12, LAYERS), blk, 0, stream>>>(Wv, (size_t)DIM * DIM, WqkvT, (size_t)QKVLD * DIM, DIM, DIM, 2 * DIM);
    w_transpose64<<<dim3(12, 12, LAYERS), blk, 0, stream>>>(Wo, (size_t)DIM * DIM, WoT, (size_t)DIM * DIM, DIM, DIM, 0);
    w_transpose64<<<dim3(48, 12, LAYERS), blk, 0, stream>>>(Wi, (size_t)DIM * FFDIM, WiT, (size_t)FFDIM * DIM, FFDIM, DIM, 0);
    w_transpose64<<<dim3(12, 48, LAYERS), blk, 0, stream>>>(Wo2, (size_t)FFDIM * DIM, Wo2T, (size_t)DIM * FFDIM, DIM, FFDIM, 0);
    build_bqkv<<<LAYERS, blk, 0, stream>>>(bq, bk, bv, bqkv);

    for (int pass = 0; pass < 2; ++pass) {
        embed_ln_kernel<<<MTOK, blk, 0, stream>>>(ids, wemb, pemb, emb_g, emb_b, h, h_bf);
        for (int l = 0; l < LAYERS; ++l) {
            const u16* WqkvT_l = WqkvT + (size_t)l * QKVLD * DIM;
            const u16* WoT_l   = WoT   + (size_t)l * DIM * DIM;
            const u16* WiT_l   = WiT   + (size_t)l * FFDIM * DIM;
            const u16* Wo2T_l  = Wo2T  + (size_t)l * DIM * FFDIM;
            const float* bqkv_l = bqkv + (size_t)l * QKVLD;
            const float* bo_l  = bo  + (size_t)l * DIM;
            const float* bi_l  = bi  + (size_t)l * FFDIM;
            const float* bo2_l = bo2 + (size_t)l * DIM;
            const float* g1_l  = g1  + (size_t)l * DIM;
            const float* b1_l  = b1  + (size_t)l * DIM;
            const float* g2_l  = g2  + (size_t)l * DIM;
            const float* b2_l  = b2  + (size_t)l * DIM;

            if (pass == 0) {
                gemm_qkv<0><<<dim3(QKVLD / 128, MTOK / 128), blk, 0, stream>>>(
                    h_bf, WqkvT_l, bqkv_l, qkv_bf, vT,
                    nullptr, nullptr, nullptr, nullptr, nullptr, l);
            } else {
                lora_t_kernel<<<dim3(MTOK / 64, 2), blk, 0, stream>>>(h, qA, vA, task, l, tq, tv);
                gemm_qkv<1><<<dim3(QKVLD / 128, MTOK / 128), blk, 0, stream>>>(
                    h_bf, WqkvT_l, bqkv_l, qkv_bf, vT,
                    tq, tv, qB, vB, task, l);
            }
            attn_fused<<<dim3(4 * ZB), blk, 0, stream>>>(qkv_bf, vT, mask, o_bf);
            gemm_mfma<64, 128, 0, 1><<<dim3(DIM / 128, MTOK / 64), blk, 0, stream>>>(
                o_bf, DIM, WoT_l, DIM, bo_l, nullptr, h2b, DIM, DIM);
            add_ln_kernel<<<MTOK, blk, 0, stream>>>(h, h2b, g1_l, b1_l, h_bf);
            gemm_mfma<128, 128, 1, 1><<<dim3(FFDIM / 128, MTOK / 128), blk, 0, stream>>>(
                h_bf, DIM, WiT_l, DIM, bi_l, nullptr, ffb_bf, FFDIM, DIM);
            gemm_mfma<64, 128, 0, 1><<<dim3(DIM / 128, MTOK / 64), blk, 0, stream>>>(
                ffb_bf, FFDIM, Wo2T_l, FFDIM, bo2_l, nullptr, h2b, DIM, FFDIM);
            add_ln_kernel<<<MTOK, blk, 0, stream>>>(h, h2b, g2_l, b2_l, h_bf);
        }
        if (pass == 0) {
            head1_kernel<0><<<dim3(12, BATCH), blk, 0, stream>>>(h, rW1, rb1, nullptr, y1);
            router_fin<<<BATCH, blk, 0, stream>>>(y1, rW2, rb2, temp, out, task);
        } else {
            head1_kernel<1><<<dim3(12, BATCH), blk, 0, stream>>>(h, cW1, cb1, task, y1);
            cls_fin<<<BATCH, blk, 0, stream>>>(y1, cW2, cb2, task, out + BATCH * TASKS);
        }
    }
}

// Round 10
// 3255.061 us; speedup vs baseline: 6.0741x; 1.1158x over previous
//
#include <hip/hip_runtime.h>
#include <math.h>

#define DIM 768
#define LAYERS 12
#define NH 12
#define HDIM 64
#define FFDIM 3072
#define SEQ 256
#define BATCH 8
#define MTOK (BATCH*SEQ)   // 2048
#define TASKS 3
#define LRANK 16
#define LORA_SC 2.0f
#define QKVLD 2304
#define ZB (BATCH*NH)      // 96

typedef unsigned short u16;
typedef __attribute__((ext_vector_type(8))) short short8;
typedef __attribute__((ext_vector_type(4))) float floatx4;
typedef __attribute__((ext_vector_type(4))) unsigned short u16x4;

__device__ __forceinline__ u16 f2bf(float f) {
    unsigned int u = __float_as_uint(f);
    u = (u + 0x7fff + ((u >> 16) & 1)) >> 16;
    return (u16)u;
}
__device__ __forceinline__ float bf2f(u16 v) {
    return __uint_as_float(((unsigned)v) << 16);
}

__device__ __forceinline__ float geluf(float x) {
    float u = 0.7978845608028654f * (x + 0.044715f * x * x * x);
    u = fminf(fmaxf(u, -15.f), 15.f);
    float e = __expf(2.f * u);
    float th = (e - 1.f) / (e + 1.f);
    return 0.5f * x * (1.f + th);
}

__device__ __forceinline__ float block_sum256(float v, volatile float* sb4) {
    #pragma unroll
    for (int o = 32; o; o >>= 1) v += __shfl_down(v, o);
    int w = threadIdx.x >> 6;
    if ((threadIdx.x & 63) == 0) sb4[w] = v;
    __syncthreads();
    float total = sb4[0] + sb4[1] + sb4[2] + sb4[3];
    __syncthreads();
    return total;
}

// XCD-aware bijective block swizzle (nwg divisible by 8 at all call sites)
__device__ __forceinline__ void xcd_map(int* bx, int* by) {
    int gx = gridDim.x;
    int nwg = gx * gridDim.y;
    int orig = blockIdx.y * gx + blockIdx.x;
    int swz = (orig & 7) * (nwg >> 3) + (orig >> 3);
    *bx = swz % gx; *by = swz / gx;
}

// ============ weight transpose fp32 [K][N] -> bf16 [row_off+N][K], 64x64 ============
__global__ __launch_bounds__(256) void w_transpose64(
    const float* __restrict__ src, size_t src_ls,
    u16* __restrict__ dst, size_t dst_ls, int N, int dstld, int row_off) {
    __shared__ float tile[64][65];
    int l = blockIdx.z;
    int k0 = blockIdx.y * 64, n0 = blockIdx.x * 64;
    int t = threadIdx.x;
    int r = t >> 4, c4 = (t & 15) * 4;
    const float* s = src + (size_t)l * src_ls + (size_t)k0 * N + n0;
    #pragma unroll
    for (int i = 0; i < 4; ++i) {
        float4 v = *(const float4*)&s[(size_t)(r + i * 16) * N + c4];
        tile[r + i * 16][c4 + 0] = v.x; tile[r + i * 16][c4 + 1] = v.y;
        tile[r + i * 16][c4 + 2] = v.z; tile[r + i * 16][c4 + 3] = v.w;
    }
    __syncthreads();
    u16* d = dst + (size_t)l * dst_ls;
    #pragma unroll
    for (int i = 0; i < 4; ++i) {
        int n = r + i * 16;
        u16x4 o;
        o[0] = f2bf(tile[c4 + 0][n]); o[1] = f2bf(tile[c4 + 1][n]);
        o[2] = f2bf(tile[c4 + 2][n]); o[3] = f2bf(tile[c4 + 3][n]);
        *(u16x4*)&d[(size_t)(row_off + n0 + n) * dstld + k0 + c4] = o;
    }
}

__global__ __launch_bounds__(256) void build_bqkv(
    const float* __restrict__ bq, const float* __restrict__ bk,
    const float* __restrict__ bv, float* __restrict__ bqkv) {
    int l = blockIdx.x;
    for (int i = threadIdx.x; i < QKVLD; i += 256) {
        float v = i < DIM ? bq[l * DIM + i]
                : (i < 2 * DIM ? bk[l * DIM + i - DIM] : bv[l * DIM + i - 2 * DIM]);
        bqkv[(size_t)l * QKVLD + i] = v;
    }
}

// ============ embedding + LN (fp32 + bf16 out) ============
__global__ __launch_bounds__(256) void embed_ln_kernel(
    const int* __restrict__ ids, const float* __restrict__ wemb,
    const float* __restrict__ pemb, const float* __restrict__ g,
    const float* __restrict__ bb, float* __restrict__ out, u16* __restrict__ out_bf) {
    __shared__ float sb[4];
    int m = blockIdx.x;
    int s = m & (SEQ - 1);
    int id = ids[m];
    int t = threadIdx.x;
    float x[3];
    float sum = 0.f;
    #pragma unroll
    for (int j = 0; j < 3; ++j) {
        int d = t + j * 256;
        x[j] = wemb[(size_t)id * DIM + d] + pemb[(size_t)(s + 2) * DIM + d];
        sum += x[j];
    }
    float mean = block_sum256(sum, sb) * (1.0f / DIM);
    float vs = 0.f;
    #pragma unroll
    for (int j = 0; j < 3; ++j) { float c = x[j] - mean; vs += c * c; }
    float var = block_sum256(vs, sb) * (1.0f / DIM);
    float rstd = rsqrtf(var + 1e-5f);
    #pragma unroll
    for (int j = 0; j < 3; ++j) {
        int d = t + j * 256;
        float r = (x[j] - mean) * rstd * g[d] + bb[d];
        out[(size_t)m * DIM + d] = r;
        out_bf[(size_t)m * DIM + d] = f2bf(r);
    }
}

// ============ residual add (bf16 proj) + LN in place, + bf16 out ============
__global__ __launch_bounds__(256) void add_ln_kernel(
    float* __restrict__ h, const u16* __restrict__ proj,
    const float* __restrict__ g, const float* __restrict__ bb, u16* __restrict__ h_bf) {
    __shared__ float sb[4];
    int m = blockIdx.x;
    int t = threadIdx.x;
    float x[3];
    float sum = 0.f;
    #pragma unroll
    for (int j = 0; j < 3; ++j) {
        int d = t + j * 256;
        x[j] = h[(size_t)m * DIM + d] + bf2f(proj[(size_t)m * DIM + d]);
        sum += x[j];
    }
    float mean = block_sum256(sum, sb) * (1.0f / DIM);
    float vs = 0.f;
    #pragma unroll
    for (int j = 0; j < 3; ++j) { float c = x[j] - mean; vs += c * c; }
    float var = block_sum256(vs, sb) * (1.0f / DIM);
    float rstd = rsqrtf(var + 1e-5f);
    #pragma unroll
    for (int j = 0; j < 3; ++j) {
        int d = t + j * 256;
        float r = (x[j] - mean) * rstd * g[d] + bb[d];
        h[(size_t)m * DIM + d] = r;
        h_bf[(size_t)m * DIM + d] = f2bf(r);
    }
}

// ============ MFMA GEMM core (double-buffered, counted vmcnt) ============
template<int ROWS>
__device__ __forceinline__ void stage_tile(const u16* srcbase, int ldk,
                                           u16* ldsbase, int wave, int lane) {
    int rin = lane >> 3, slot = lane & 7;
    #pragma unroll
    for (int c0 = 0; c0 < ROWS / 8; c0 += 4) {
        int c = c0 + wave;
        int r = c * 8 + rin;
        int scol = ((slot ^ (r & 7)) << 3);
        const u16* src = srcbase + (size_t)r * ldk + scol;
        __builtin_amdgcn_global_load_lds(
            (const __attribute__((address_space(1))) unsigned int*)src,
            (__attribute__((address_space(3))) unsigned int*)(ldsbase + (size_t)c * 512 + lane * 8),
            16, 0, 0);
    }
}

__device__ __forceinline__ short8 frag_read(const u16* ldsbase, int r, int s) {
    return *(const short8*)(ldsbase + r * 64 + (((s ^ (r & 7)) << 3)));
}

// K/64 must be EVEN at all call sites (K=768 -> 12, K=3072 -> 48).
template<int BM, int BN>
__device__ __forceinline__ void gemm_core(
    const u16* __restrict__ A, int lda, const u16* __restrict__ B, int ldb,
    int K, int m0, int n0, u16* lds, floatx4 (&acc)[BM / 32][BN / 32]) {
    constexpr int TILE = (BM + BN) * 64;
    constexpr int NL = BM / 32 + BN / 32;
    u16* buf0 = lds;
    u16* buf1 = lds + TILE;
    int t = threadIdx.x, lane = t & 63, wave = t >> 6;
    int wr = wave >> 1, wc = wave & 1;
    constexpr int FM = BM / 32, FN = BN / 32;
    int wm0 = wr * (BM / 2), wn0 = wc * (BN / 2);
    #pragma unroll
    for (int i = 0; i < FM; ++i)
        #pragma unroll
        for (int j = 0; j < FN; ++j)
            acc[i][j] = (floatx4){0.f, 0.f, 0.f, 0.f};
    int lr = lane & 15, kg = lane >> 4;
    const u16* Abase = A + (size_t)m0 * lda;
    const u16* Bbase = B + (size_t)n0 * ldb;

    auto stage = [&](u16* dst, int k0) {
        stage_tile<BM>(Abase + k0, lda, dst, wave, lane);
        stage_tile<BN>(Bbase + k0, ldb, dst + BM * 64, wave, lane);
    };
    auto compute = [&](const u16* buf) {
        const u16* As = buf;
        const u16* Bs = buf + BM * 64;
        #pragma unroll
        for (int kk = 0; kk < 2; ++kk) {
            short8 af[FM], bfr[FN];
            #pragma unroll
            for (int mi = 0; mi < FM; ++mi)
                af[mi] = frag_read(As, wm0 + mi * 16 + lr, kk * 4 + kg);
            #pragma unroll
            for (int ni = 0; ni < FN; ++ni)
                bfr[ni] = frag_read(Bs, wn0 + ni * 16 + lr, kk * 4 + kg);
            #pragma unroll
            for (int mi = 0; mi < FM; ++mi)
                #pragma unroll
                for (int ni = 0; ni < FN; ++ni)
                    acc[mi][ni] = __builtin_amdgcn_mfma_f32_16x16x32_bf16(
                        af[mi], bfr[ni], acc[mi][ni], 0, 0, 0);
        }
    };

    int nt = K / 64;
    stage(buf0, 0);
    for (int ti = 0; ti < nt; ti += 2) {
        stage(buf1, (ti + 1) * 64);
        asm volatile("s_waitcnt vmcnt(%0)" :: "n"(NL) : "memory");
        __builtin_amdgcn_s_barrier();
        __builtin_amdgcn_sched_barrier(0);
        compute(buf0);
        __builtin_amdgcn_sched_barrier(0);
        __builtin_amdgcn_s_barrier();
        if (ti + 2 < nt) {
            stage(buf0, (ti + 2) * 64);
            asm volatile("s_waitcnt vmcnt(%0)" :: "n"(NL) : "memory");
        } else {
            asm volatile("s_waitcnt vmcnt(0)" ::: "memory");
        }
        __builtin_amdgcn_s_barrier();
        __builtin_amdgcn_sched_barrier(0);
        compute(buf1);
        __builtin_amdgcn_sched_barrier(0);
        __builtin_amdgcn_s_barrier();
    }
}

// ---- standard GEMM kernel ----
template<int BM, int BN, int ACT, int OUTMODE>   // OUTMODE: 0=f32, 1=bf16
__global__ __launch_bounds__(256) void gemm_mfma(
    const u16* __restrict__ A, int lda, const u16* __restrict__ B, int ldb,
    const float* __restrict__ bias, float* __restrict__ Cf, u16* __restrict__ Cb,
    int ldc, int K) {
    __shared__ u16 lds[2 * (BM + BN) * 64];
    constexpr int FM = BM / 32, FN = BN / 32;
    floatx4 acc[FM][FN];
    int bx, by;
    xcd_map(&bx, &by);
    int m0 = by * BM, n0 = bx * BN;
    gemm_core<BM, BN>(A, lda, B, ldb, K, m0, n0, lds, acc);
    int t = threadIdx.x, lane = t & 63, wave = t >> 6;
    int wr = wave >> 1, wc = wave & 1;
    int wm0 = wr * (BM / 2), wn0 = wc * (BN / 2);
    int cr = (lane >> 4) * 4, cc = lane & 15;
    #pragma unroll
    for (int mi = 0; mi < FM; ++mi) {
        #pragma unroll
        for (int ni = 0; ni < FN; ++ni) {
            int col = n0 + wn0 + ni * 16 + cc;
            float bsv = bias ? bias[col] : 0.f;
            #pragma unroll
            for (int j = 0; j < 4; ++j) {
                int row = m0 + wm0 + mi * 16 + cr + j;
                float r = acc[mi][ni][j] + bsv;
                if (ACT == 1) r = geluf(r);
                if (OUTMODE == 0) Cf[(size_t)row * ldc + col] = r;
                else Cb[(size_t)row * ldc + col] = f2bf(r);
            }
        }
    }
}

// ---- QKV GEMM (64x128): bias, optional fused LoRA, bf16 out, fused vT scatter ----
template<int LORA>
__global__ __launch_bounds__(256) void gemm_qkv(
    const u16* __restrict__ A, const u16* __restrict__ Bw,
    const float* __restrict__ bias, u16* __restrict__ qkv_bf,
    u16* __restrict__ vT,
    const float* __restrict__ tq, const float* __restrict__ tv,
    const float* __restrict__ qBb, const float* __restrict__ vBb,
    const int* __restrict__ taskp, int layer) {
    __shared__ u16 lds[2 * (64 + 128) * 64];
    floatx4 acc[2][4];
    int bx, by;
    xcd_map(&bx, &by);
    int m0 = by * 64, n0 = bx * 128;
    gemm_core<64, 128>(A, DIM, Bw, DIM, DIM, m0, n0, lds, acc);
    int t = threadIdx.x, lane = t & 63, wave = t >> 6;
    int wr = wave >> 1, wc = wave & 1;
    int wm0 = wr * 32, wn0 = wc * 64;
    int cr = (lane >> 4) * 4, cc = lane & 15;
    const float* tvec = nullptr;
    const float* Bmat = nullptr;
    if (LORA) {
        int tk = taskp[m0 >> 8];
        if (n0 < DIM) {
            tvec = tq;
            Bmat = qBb + ((size_t)tk * LAYERS + layer) * DIM * LRANK;
        } else if (n0 >= 2 * DIM) {
            tvec = tv;
            Bmat = vBb + ((size_t)tk * LAYERS + layer) * DIM * LRANK - (size_t)2 * DIM * LRANK;
        }
    }
    bool vrange = (n0 >= 2 * DIM);
    #pragma unroll
    for (int mi = 0; mi < 2; ++mi) {
        #pragma unroll
        for (int j = 0; j < 4; ++j) {
            int row = m0 + wm0 + mi * 16 + cr + j;
            float4 t0, t1, t2, t3;
            if (LORA && tvec) {
                const float* tp = tvec + (size_t)row * LRANK;
                t0 = *(const float4*)(tp + 0);  t1 = *(const float4*)(tp + 4);
                t2 = *(const float4*)(tp + 8);  t3 = *(const float4*)(tp + 12);
            }
            #pragma unroll
            for (int ni = 0; ni < 4; ++ni) {
                int col = n0 + wn0 + ni * 16 + cc;
                float r = acc[mi][ni][j] + bias[col];
                if (LORA && tvec) {
                    const float* bp = Bmat + (size_t)col * LRANK;
                    float4 b0 = *(const float4*)(bp + 0),  b1 = *(const float4*)(bp + 4);
                    float4 b2 = *(const float4*)(bp + 8),  b3 = *(const float4*)(bp + 12);
                    float d = t0.x * b0.x + t0.y * b0.y + t0.z * b0.z + t0.w * b0.w
                            + t1.x * b1.x + t1.y * b1.y + t1.z * b1.z + t1.w * b1.w
                            + t2.x * b2.x + t2.y * b2.y + t2.z * b2.z + t2.w * b2.w
                            + t3.x * b3.x + t3.y * b3.y + t3.z * b3.z + t3.w * b3.w;
                    r += LORA_SC * d;
                }
                u16 rb = f2bf(r);
                qkv_bf[(size_t)row * QKVLD + col] = rb;
                if (vrange) {
                    int vcol = col - 2 * DIM;
                    int hh = vcol >> 6, dd = vcol & 63;
                    int bb = row >> 8, kpos = row & 255;
                    vT[((size_t)(bb * NH + hh) * HDIM + dd) * SEQ + kpos] = rb;
                }
            }
        }
    }
}

// ============ fused attention (1D grid, XCD-pinned: batch b -> XCD b) ============
__device__ __forceinline__ int lds256_idx(int r, int col) {
    int sub = col >> 6, inner = col & 63;
    return r * 256 + sub * 64 + ((((inner >> 3) ^ (r & 7))) << 3) + (inner & 7);
}
__device__ __forceinline__ short8 frag_read256(const u16* base, int r, int kk, int kg) {
    int col = kk * 32 + kg * 8;
    int sub = col >> 6, slot = (col & 63) >> 3;
    return *(const short8*)(base + r * 256 + sub * 64 + ((slot ^ (r & 7)) << 3));
}

__global__ __launch_bounds__(256) void attn_fused(
    const u16* __restrict__ qkv_bf, const u16* __restrict__ vT,
    const int* __restrict__ mask, u16* __restrict__ o_bf) {
    __shared__ u16 lds[256 * 64 + 64 * 256];
    u16* KV = lds;
    u16* P = lds + 256 * 64;
    int i = blockIdx.x;
    int xg = i & 7, j2 = i >> 3;
    int z = xg * 12 + (j2 >> 2);
    int qt = j2 & 3;
    int b = z / NH, h = z % NH;
    int t = threadIdx.x, lane = t & 63, w = t >> 6;
    int cc = lane & 15, q4 = lane >> 4;

    float mb[16];
    #pragma unroll
    for (int ni = 0; ni < 16; ++ni)
        mb[ni] = (1.0f - (float)mask[b * SEQ + ni * 16 + cc]) * -1e9f;

    int qrow = b * SEQ + qt * 64 + w * 16 + cc;
    const u16* qp = qkv_bf + (size_t)qrow * QKVLD + h * HDIM + q4 * 8;
    short8 qa0 = *(const short8*)(qp);
    short8 qa1 = *(const short8*)(qp + 32);

    stage_tile<256>(qkv_bf + (size_t)(b * SEQ) * QKVLD + DIM + h * HDIM, QKVLD, KV, w, lane);
    __syncthreads();

    floatx4 s[16];
    #pragma unroll
    for (int ni = 0; ni < 16; ++ni) s[ni] = (floatx4){0.f, 0.f, 0.f, 0.f};
    #pragma unroll
    for (int kk = 0; kk < 2; ++kk) {
        short8 qa = kk == 0 ? qa0 : qa1;
        #pragma unroll
        for (int ni = 0; ni < 16; ++ni) {
            short8 kf = frag_read(KV, ni * 16 + cc, kk * 4 + q4);
            s[ni] = __builtin_amdgcn_mfma_f32_16x16x32_bf16(qa, kf, s[ni], 0, 0, 0);
        }
    }

    float pv[16][4];
    float mrow[4] = {-1e30f, -1e30f, -1e30f, -1e30f};
    #pragma unroll
    for (int ni = 0; ni < 16; ++ni)
        #pragma unroll
        for (int j = 0; j < 4; ++j) {
            float v = s[ni][j] * 0.125f + mb[ni];
            pv[ni][j] = v;
            mrow[j] = fmaxf(mrow[j], v);
        }
    #pragma unroll
    for (int o = 1; o < 16; o <<= 1)
        #pragma unroll
        for (int j = 0; j < 4; ++j) mrow[j] = fmaxf(mrow[j], __shfl_xor(mrow[j], o));
    float srow[4] = {0.f, 0.f, 0.f, 0.f};
    #pragma unroll
    for (int ni = 0; ni < 16; ++ni)
        #pragma unroll
        for (int j = 0; j < 4; ++j) {
            float e = __expf(pv[ni][j] - mrow[j]);
            pv[ni][j] = e;
            srow[j] += e;
        }
    #pragma unroll
    for (int o = 1; o < 16; o <<= 1)
        #pragma unroll
        for (int j = 0; j < 4; ++j) srow[j] += __shfl_xor(srow[j], o);
    float inv[4];
    #pragma unroll
    for (int j = 0; j < 4; ++j) inv[j] = 1.0f / srow[j];

    u16* Pw = P + w * 16 * 256;
    #pragma unroll
    for (int ni = 0; ni < 16; ++ni)
        #pragma unroll
        for (int j = 0; j < 4; ++j)
            Pw[lds256_idx(q4 * 4 + j, ni * 16 + cc)] = f2bf(pv[ni][j] * inv[j]);
    __syncthreads();

    {
        const u16* vz = vT + (size_t)z * HDIM * SEQ;
        int rin = lane >> 3, slot = lane & 7;
        #pragma unroll
        for (int c0 = 0; c0 < 32; c0 += 4) {
            int c = c0 + w;
            int vrow = c * 8 + rin;
            int d = vrow >> 2, sub = vrow & 3;
            const u16* src = vz + d * 256 + sub * 64 + (((slot ^ (d & 7))) << 3);
            __builtin_amdgcn_global_load_lds(
                (const __attribute__((address_space(1))) unsigned int*)src,
                (__attribute__((address_space(3))) unsigned int*)(KV + c * 512 + lane * 8),
                16, 0, 0);
        }
    }
    __syncthreads();

    floatx4 oa[4];
    #pragma unroll
    for (int ni = 0; ni < 4; ++ni) oa[ni] = (floatx4){0.f, 0.f, 0.f, 0.f};
    #pragma unroll
    for (int kk = 0; kk < 8; ++kk) {
        short8 pf = frag_read256(Pw, cc, kk, q4);
        #pragma unroll
        for (int ni = 0; ni < 4; ++ni) {
            short8 vf = frag_read256(KV, ni * 16 + cc, kk, q4);
            oa[ni] = __builtin_amdgcn_mfma_f32_16x16x32_bf16(pf, vf, oa[ni], 0, 0, 0);
        }
    }
    #pragma unroll
    for (int ni = 0; ni < 4; ++ni)
        #pragma unroll
        for (int j = 0; j < 4; ++j) {
            int m = b * SEQ + qt * 64 + w * 16 + q4 * 4 + j;
            o_bf[(size_t)m * DIM + h * HDIM + ni * 16 + cc] = f2bf(oa[ni][j]);
        }
}

// ============ LoRA t-vectors ============
__global__ __launch_bounds__(256) void lora_t_kernel(
    const float* __restrict__ h, const float* __restrict__ qA,
    const float* __restrict__ vA, const int* __restrict__ task,
    int layer, float* __restrict__ tq, float* __restrict__ tv) {
    int which = blockIdx.y;
    const float* Ab = which ? vA : qA;
    float* tout = which ? tv : tq;
    int m0 = blockIdx.x * 64;
    int tk = task[m0 >> 8];
    const float* Ap = Ab + ((size_t)tk * LAYERS + layer) * LRANK * DIM;
    int t = threadIdx.x;
    int row = t & 63, rb = t >> 6;
    float s[4] = {0.f, 0.f, 0.f, 0.f};
    const float* hrow = h + (size_t)(m0 + row) * DIM;
    for (int d = 0; d < DIM; d += 4) {
        float4 hv = *(const float4*)&hrow[d];
        #pragma unroll
        for (int i = 0; i < 4; ++i) {
            float4 av = *(const float4*)&Ap[(size_t)(rb + i * 4) * DIM + d];
            s[i] += hv.x * av.x + hv.y * av.y + hv.z * av.z + hv.w * av.w;
        }
    }
    #pragma unroll
    for (int i = 0; i < 4; ++i)
        tout[(size_t)(m0 + row) * LRANK + rb + i * 4] = s[i];
}

// ============ heads: stage 1 (parallel matvec y1 = act(cls@W1+b1)) ============
template<int TANH>
__global__ __launch_bounds__(256) void head1_kernel(
    const float* __restrict__ h, const float* __restrict__ W1base,
    const float* __restrict__ b1base, const int* __restrict__ taskp,
    float* __restrict__ y1) {
    int b = blockIdx.y;
    int c0 = blockIdx.x * 64;
    int tk = taskp ? taskp[b] : 0;
    const float* W1 = W1base + (size_t)tk * DIM * DIM;
    const float* b1 = b1base + (size_t)tk * DIM;
    __shared__ float cls[DIM];
    __shared__ float part[4][64];
    int t = threadIdx.x;
    for (int j = t; j < DIM; j += 256) cls[j] = h[(size_t)(b * SEQ) * DIM + j];
    __syncthreads();
    int col = c0 + (t & 63);
    int seg = t >> 6;
    float s = 0.f;
    #pragma unroll 4
    for (int d = seg * 192; d < seg * 192 + 192; ++d)
        s += cls[d] * W1[(size_t)d * DIM + col];
    part[seg][t & 63] = s;
    __syncthreads();
    if (t < 64) {
        float r = part[0][t] + part[1][t] + part[2][t] + part[3][t] + b1[c0 + t];
        y1[(size_t)b * DIM + c0 + t] = TANH ? tanhf(r) : fmaxf(r, 0.f);
    }
}

// ============ router finalize ============
__global__ __launch_bounds__(256) void router_fin(
    const float* __restrict__ y1, const float* __restrict__ W2,
    const float* __restrict__ b2, const float* __restrict__ temp,
    float* __restrict__ out_logits, int* __restrict__ task) {
    int b = blockIdx.x;
    int t = threadIdx.x;
    __shared__ float red[3][4];
    float p[3] = {0.f, 0.f, 0.f};
    #pragma unroll
    for (int j = 0; j < 3; ++j) {
        int col = t + j * 256;
        float y = y1[(size_t)b * DIM + col];
        p[0] += y * W2[col * 3 + 0];
        p[1] += y * W2[col * 3 + 1];
        p[2] += y * W2[col * 3 + 2];
    }
    #pragma unroll
    for (int o = 32; o; o >>= 1) {
        p[0] += __shfl_down(p[0], o);
        p[1] += __shfl_down(p[1], o);
        p[2] += __shfl_down(p[2], o);
    }
    int w = t >> 6;
    if ((t & 63) == 0) { red[0][w] = p[0]; red[1][w] = p[1]; red[2][w] = p[2]; }
    __syncthreads();
    if (t == 0) {
        float tt = fmaxf(temp[0], 0.05f);
        float l[3];
        #pragma unroll
        for (int c = 0; c < 3; ++c) {
            l[c] = (red[c][0] + red[c][1] + red[c][2] + red[c][3] + b2[c]) / tt;
            out_logits[b * 3 + c] = l[c];
        }
        int bt = 0; float bv = l[0];
        if (l[1] > bv) { bv = l[1]; bt = 1; }
        if (l[2] > bv) { bv = l[2]; bt = 2; }
        task[b] = bt;
    }
}

// ============ classifier finalize ============
__global__ __launch_bounds__(256) void cls_fin(
    const float* __restrict__ y1, const float* __restrict__ cW2,
    const float* __restrict__ cb2, const int* __restrict__ task,
    float* __restrict__ out) {
    int b = blockIdx.x;
    int t = threadIdx.x;
    int tk = task[b];
    const float* W2 = cW2 + (size_t)tk * DIM * 2;
    const float* b2 = cb2 + tk * 2;
    __shared__ float red[2][4];
    float p[2] = {0.f, 0.f};
    #pragma unroll
    for (int j = 0; j < 3; ++j) {
        int col = t + j * 256;
        float y = y1[(size_t)b * DIM + col];
        p[0] += y * W2[col * 2 + 0];
        p[1] += y * W2[col * 2 + 1];
    }
    #pragma unroll
    for (int o = 32; o; o >>= 1) {
        p[0] += __shfl_down(p[0], o);
        p[1] += __shfl_down(p[1], o);
    }
    int w = t >> 6;
    if ((t & 63) == 0) { red[0][w] = p[0]; red[1][w] = p[1]; }
    __syncthreads();
    if (t == 0) {
        #pragma unroll
        for (int c = 0; c < 2; ++c)
            out[b * 2 + c] = red[c][0] + red[c][1] + red[c][2] + red[c][3] + b2[c];
    }
}

extern "C" void kernel_launch(void* const* d_in, const int* in_sizes, int n_in,
                              void* d_out, int out_size, void* d_ws, size_t ws_size,
                              hipStream_t stream) {
    (void)in_sizes; (void)n_in; (void)out_size; (void)ws_size;
    const int*   ids   = (const int*)d_in[0];
    const int*   mask  = (const int*)d_in[1];
    const float* wemb  = (const float*)d_in[2];
    const float* pemb  = (const float*)d_in[3];
    const float* emb_g = (const float*)d_in[4];
    const float* emb_b = (const float*)d_in[5];
    const float* Wq    = (const float*)d_in[6];
    const float* Wk    = (const float*)d_in[7];
    const float* Wv    = (const float*)d_in[8];
    const float* Wo    = (const float*)d_in[9];
    const float* Wi    = (const float*)d_in[10];
    const float* Wo2   = (const float*)d_in[11];
    const float* bq    = (const float*)d_in[12];
    const float* bk    = (const float*)d_in[13];
    const float* bv    = (const float*)d_in[14];
    const float* bo    = (const float*)d_in[15];
    const float* bi    = (const float*)d_in[16];
    const float* bo2   = (const float*)d_in[17];
    const float* g1    = (const float*)d_in[18];
    const float* b1    = (const float*)d_in[19];
    const float* g2    = (const float*)d_in[20];
    const float* b2    = (const float*)d_in[21];
    const float* rW1   = (const float*)d_in[22];
    const float* rb1   = (const float*)d_in[23];
    const float* rW2   = (const float*)d_in[24];
    const float* rb2   = (const float*)d_in[25];
    const float* temp  = (const float*)d_in[26];
    const float* qA    = (const float*)d_in[27];
    const float* qB    = (const float*)d_in[28];
    const float* vA    = (const float*)d_in[29];
    const float* vB    = (const float*)d_in[30];
    const float* cW1   = (const float*)d_in[31];
    const float* cb1   = (const float*)d_in[32];
    const float* cW2   = (const float*)d_in[33];
    const float* cb2   = (const float*)d_in[34];
    float* out = (float*)d_out;

    const size_t MD = (size_t)MTOK * DIM;
    char* p = (char*)d_ws;
    auto alloc = [&](size_t bytes) { char* r = p; p += (bytes + 255) & ~(size_t)255; return r; };
    float* h      = (float*)alloc(MD * 4);
    u16* h2b    = (u16*)alloc(MD * 2);
    u16* h_bf   = (u16*)alloc(MD * 2);
    u16* o_bf   = (u16*)alloc(MD * 2);
    u16* qkv_bf = (u16*)alloc((size_t)MTOK * QKVLD * 2);
    u16* ffb_bf = (u16*)alloc((size_t)MTOK * FFDIM * 2);
    u16* vT     = (u16*)alloc((size_t)ZB * HDIM * SEQ * 2);
    float* tq   = (float*)alloc((size_t)MTOK * LRANK * 4);
    float* tv   = (float*)alloc((size_t)MTOK * LRANK * 4);
    float* bqkv = (float*)alloc((size_t)LAYERS * QKVLD * 4);
    float* y1   = (float*)alloc((size_t)BATCH * DIM * 4);
    int* task   = (int*)alloc(256);
    u16* WqkvT  = (u16*)alloc((size_t)LAYERS * QKVLD * DIM * 2);
    u16* WoT    = (u16*)alloc((size_t)LAYERS * DIM * DIM * 2);
    u16* WiT    = (u16*)alloc((size_t)LAYERS * FFDIM * DIM * 2);
    u16* Wo2T   = (u16*)alloc((size_t)LAYERS * DIM * FFDIM * 2);

    dim3 blk(256);
    // --- weight prep (bf16, [N][K]) ---
    w_transpose64<<<dim3(12, 12, LAYERS), blk, 0, stream>>>(Wq, (size_t)DIM * DIM, WqkvT, (size_t)QKVLD * DIM, DIM, DIM, 0);
    w_transpose64<<<dim3(12, 12, LAYERS), blk, 0, stream>>>(Wk, (size_t)DIM * DIM, WqkvT, (size_t)QKVLD * DIM, DIM, DIM, DIM);
    w_transpose64<<<dim3(12, 12, LAYERS), blk, 0, stream>>>(Wv, (size_t)DIM * DIM, WqkvT, (size_t)QKVLD * DIM, DIM, DIM, 2 * DIM);
    w_transpose64<<<dim3(12, 12, LAYERS), blk, 0, stream>>>(Wo, (size_t)DIM * DIM, WoT, (size_t)DIM * DIM, DIM, DIM, 0);
    w_transpose64<<<dim3(48, 12, LAYERS), blk, 0, stream>>>(Wi, (size_t)DIM * FFDIM, WiT, (size_t)FFDIM * DIM, FFDIM, DIM, 0);
    w_transpose64<<<dim3(12, 48, LAYERS), blk, 0, stream>>>(Wo2, (size_t)FFDIM * DIM, Wo2T, (size_t)DIM * FFDIM, DIM, FFDIM, 0);
    build_bqkv<<<LAYERS, blk, 0, stream>>>(bq, bk, bv, bqkv);

    for (int pass = 0; pass < 2; ++pass) {
        embed_ln_kernel<<<MTOK, blk, 0, stream>>>(ids, wemb, pemb, emb_g, emb_b, h, h_bf);
        for (int l = 0; l < LAYERS; ++l) {
            const u16* WqkvT_l = WqkvT + (size_t)l * QKVLD * DIM;
            const u16* WoT_l   = WoT   + (size_t)l * DIM * DIM;
            const u16* WiT_l   = WiT   + (size_t)l * FFDIM * DIM;
            const u16* Wo2T_l  = Wo2T  + (size_t)l * DIM * FFDIM;
            const float* bqkv_l = bqkv + (size_t)l * QKVLD;
            const float* bo_l  = bo  + (size_t)l * DIM;
            const float* bi_l  = bi  + (size_t)l * FFDIM;
            const float* bo2_l = bo2 + (size_t)l * DIM;
            const float* g1_l  = g1  + (size_t)l * DIM;
            const float* b1_l  = b1  + (size_t)l * DIM;
            const float* g2_l  = g2  + (size_t)l * DIM;
            const float* b2_l  = b2  + (size_t)l * DIM;

            if (pass == 0) {
                gemm_qkv<0><<<dim3(QKVLD / 128, MTOK / 64), blk, 0, stream>>>(
                    h_bf, WqkvT_l, bqkv_l, qkv_bf, vT,
                    nullptr, nullptr, nullptr, nullptr, nullptr, l);
            } else {
                lora_t_kernel<<<dim3(MTOK / 64, 2), blk, 0, stream>>>(h, qA, vA, task, l, tq, tv);
                gemm_qkv<1><<<dim3(QKVLD / 128, MTOK / 64), blk, 0, stream>>>(
                    h_bf, WqkvT_l, bqkv_l, qkv_bf, vT,
                    tq, tv, qB, vB, task, l);
            }
            attn_fused<<<dim3(4 * ZB), blk, 0, stream>>>(qkv_bf, vT, mask, o_bf);
            gemm_mfma<64, 64, 0, 1><<<dim3(DIM / 64, MTOK / 64), blk, 0, stream>>>(
                o_bf, DIM, WoT_l, DIM, bo_l, nullptr, h2b, DIM, DIM);
            add_ln_kernel<<<MTOK, blk, 0, stream>>>(h, h2b, g1_l, b1_l, h_bf);
            gemm_mfma<64, 128, 1, 1><<<dim3(FFDIM / 128, MTOK / 64), blk, 0, stream>>>(
                h_bf, DIM, WiT_l, DIM, bi_l, nullptr, ffb_bf, FFDIM, DIM);
            gemm_mfma<64, 64, 0, 1><<<dim3(DIM / 64, MTOK / 64), blk, 0, stream>>>(
                ffb_bf, FFDIM, Wo2T_l, FFDIM, bo2_l, nullptr, h2b, DIM, FFDIM);
            add_ln_kernel<<<MTOK, blk, 0, stream>>>(h, h2b, g2_l, b2_l, h_bf);
        }
        if (pass == 0) {
            head1_kernel<0><<<dim3(12, BATCH), blk, 0, stream>>>(h, rW1, rb1, nullptr, y1);
            router_fin<<<BATCH, blk, 0, stream>>>(y1, rW2, rb2, temp, out, task);
        } else {
            head1_kernel<1><<<dim3(12, BATCH), blk, 0, stream>>>(h, cW1, cb1, task, y1);
            cls_fin<<<BATCH, blk, 0, stream>>>(y1, cW2, cb2, task, out + BATCH * TASKS);
        }
    }
}